// Round 1
// baseline (534.699 us; speedup 1.0000x reference)
//
#include <hip/hip_runtime.h>
#include <hip/hip_bf16.h>
#include <stdint.h>
#include <stddef.h>

typedef __bf16 bf16_t;
typedef __bf16 bf16x8 __attribute__((ext_vector_type(8)));
typedef float  f32x4  __attribute__((ext_vector_type(4)));

static __device__ __forceinline__ f32x4 zero4() { return (f32x4){0.f, 0.f, 0.f, 0.f}; }

#define MFMA16(a, b, c) __builtin_amdgcn_mfma_f32_16x16x32_bf16((a), (b), (c), 0, 0, 0)

#define GLOAD_LDS16(gptr, lptr)                                                        \
  __builtin_amdgcn_global_load_lds((const __attribute__((address_space(1))) void*)(gptr), \
                                   (__attribute__((address_space(3))) void*)(lptr), 16, 0, 0)

// ---------------- cast x fp32 -> bf16, 8 elems/thread ----------------
__global__ __launch_bounds__(256) void k_cast(const float* __restrict__ in,
                                              bf16_t* __restrict__ out) {
  size_t i = (size_t)blockIdx.x * 256 + threadIdx.x;
  const float4* p = (const float4*)in;
  float4 a = p[i * 2 + 0];
  float4 b = p[i * 2 + 1];
  bf16x8 v;
  v[0] = (bf16_t)a.x; v[1] = (bf16_t)a.y; v[2] = (bf16_t)a.z; v[3] = (bf16_t)a.w;
  v[4] = (bf16_t)b.x; v[5] = (bf16_t)b.y; v[6] = (bf16_t)b.z; v[7] = (bf16_t)b.w;
  *(bf16x8*)(out + i * 8) = v;
}

// ------------- transpose-cast: in fp32 [R][C] -> out bf16 [C][R] -------------
__global__ __launch_bounds__(256) void k_tcast(const float* __restrict__ in,
                                               bf16_t* __restrict__ out,
                                               int R, int C) {
  __shared__ bf16_t tile[64][72];
  int c0 = blockIdx.x * 64, r0 = blockIdx.y * 64;
  int t = threadIdx.x;
  int r = t >> 2, cc = (t & 3) * 16;
  const float* src = in + (size_t)(r0 + r) * C + c0 + cc;
#pragma unroll
  for (int q = 0; q < 4; ++q) {
    float4 v = *(const float4*)(src + q * 4);
    tile[r][cc + q * 4 + 0] = (bf16_t)v.x;
    tile[r][cc + q * 4 + 1] = (bf16_t)v.y;
    tile[r][cc + q * 4 + 2] = (bf16_t)v.z;
    tile[r][cc + q * 4 + 3] = (bf16_t)v.w;
  }
  __syncthreads();
  int c = t >> 2, rr = (t & 3) * 16;
  bf16x8 o0, o1;
#pragma unroll
  for (int j = 0; j < 8; ++j) { o0[j] = tile[rr + j][c]; o1[j] = tile[rr + 8 + j][c]; }
  bf16_t* dst = out + (size_t)(c0 + c) * R + r0 + rr;
  *(bf16x8*)dst = o0;
  *(bf16x8*)(dst + 8) = o1;
}

// ------- V transpose: qkv bf16 [8192][3072] -> vT bf16 [(bh*64+d)][2048] -------
__global__ __launch_bounds__(256) void k_vtrans(const bf16_t* __restrict__ qkv,
                                                bf16_t* __restrict__ vT) {
  __shared__ bf16_t tile[64][72];
  int t0 = blockIdx.x * 64, bh = blockIdx.y;
  int b = bh >> 4, h = bh & 15;
  int t = threadIdx.x;
  int tr = t >> 2, cc = (t & 3) * 16;
  const bf16_t* src = qkv + (size_t)(b * 2048 + t0 + tr) * 3072 + 2048 + h * 64 + cc;
  bf16x8 a0 = *(const bf16x8*)src;
  bf16x8 a1 = *(const bf16x8*)(src + 8);
#pragma unroll
  for (int j = 0; j < 8; ++j) { tile[tr][cc + j] = a0[j]; tile[tr][cc + 8 + j] = a1[j]; }
  __syncthreads();
  int d = t >> 2, tt = (t & 3) * 16;
  bf16x8 o0, o1;
#pragma unroll
  for (int j = 0; j < 8; ++j) { o0[j] = tile[tt + j][d]; o1[j] = tile[tt + 8 + j][d]; }
  bf16_t* dst = vT + (size_t)(bh * 64 + d) * 2048 + t0 + tt;
  *(bf16x8*)dst = o0;
  *(bf16x8*)(dst + 8) = o1;
}

// ---------------- GEMM: C[M][N] = A[M][K] * BT[N][K]^T (+bias) ----------------
// 128x128 tile, BK=32, 4 waves (2x2), each wave 64x64 = 4x4 frags of 16x16.
template <bool BF16OUT>
__global__ __launch_bounds__(256) void k_gemm_bt(const bf16_t* __restrict__ A,
                                                 const bf16_t* __restrict__ BT,
                                                 void* __restrict__ Cout,
                                                 const float* __restrict__ bias,
                                                 int M, int N, int K) {
  __shared__ bf16_t sA[128 * 32];
  __shared__ bf16_t sB[128 * 32];
  int tid = threadIdx.x;
  int wid = tid >> 6, lane = tid & 63;
  int cl = lane & 15, gp = lane >> 4;
  int brow = blockIdx.y * 128, bcol = blockIdx.x * 128;
  int wr = wid >> 1, wc = wid & 1;
  f32x4 acc[4][4];
#pragma unroll
  for (int i = 0; i < 4; ++i)
#pragma unroll
    for (int j = 0; j < 4; ++j) acc[i][j] = zero4();

  int srow = tid >> 2;          // 0..63
  int sk = (tid & 3) * 8;       // k-element offset of this thread's 16B
  const bf16_t* gA = A + (size_t)(brow + srow) * K + sk;
  const bf16_t* gB = BT + (size_t)(bcol + srow) * K + sk;
  char* lA = (char*)sA + wid * 1024;   // wave-uniform LDS base; HW adds lane*16
  char* lB = (char*)sB + wid * 1024;

  for (int k0 = 0; k0 < K; k0 += 32) {
    __syncthreads();
    GLOAD_LDS16(gA + k0, lA);
    GLOAD_LDS16(gA + (size_t)64 * K + k0, lA + 4096);
    GLOAD_LDS16(gB + k0, lB);
    GLOAD_LDS16(gB + (size_t)64 * K + k0, lB + 4096);
    __syncthreads();
    bf16x8 af[4], bfr[4];
#pragma unroll
    for (int i = 0; i < 4; ++i)
      af[i] = *(const bf16x8*)&sA[(wr * 64 + i * 16 + cl) * 32 + gp * 8];
#pragma unroll
    for (int j = 0; j < 4; ++j)
      bfr[j] = *(const bf16x8*)&sB[(wc * 64 + j * 16 + cl) * 32 + gp * 8];
#pragma unroll
    for (int i = 0; i < 4; ++i)
#pragma unroll
      for (int j = 0; j < 4; ++j)
        acc[i][j] = MFMA16(af[i], bfr[j], acc[i][j]);
  }

#pragma unroll
  for (int i = 0; i < 4; ++i) {
    int row0 = brow + wr * 64 + i * 16 + gp * 4;
#pragma unroll
    for (int j = 0; j < 4; ++j) {
      int col = bcol + wc * 64 + j * 16 + cl;
#pragma unroll
      for (int e = 0; e < 4; ++e) {
        size_t idx = (size_t)(row0 + e) * N + col;
        if (BF16OUT)
          ((bf16_t*)Cout)[idx] = (bf16_t)acc[i][j][e];
        else
          ((float*)Cout)[idx] = acc[i][j][e] + bias[col];
      }
    }
  }
}

// ---------------- flash attention: 1 wave per (b,h,16 q-rows) ----------------
// qkv bf16 [8192][3072]: Q at col h*64, K at 1024+h*64.  vT bf16 [(bh*64+d)][2048].
__global__ __launch_bounds__(64) void k_attn(const bf16_t* __restrict__ qkv,
                                             const bf16_t* __restrict__ vT,
                                             bf16_t* __restrict__ out) {
  __shared__ bf16_t P[16 * 32];
  int qt = blockIdx.x, bh = blockIdx.y;
  int b = bh >> 4, h = bh & 15;
  int lane = threadIdx.x;
  int cl = lane & 15, gp = lane >> 4;
  int q0 = qt * 16;

  // Q fragments (A-operand): row = cl, k(=Dh) = kk*32 + gp*8 + e. scale=1/8 exact in bf16.
  const bf16_t* Qp = qkv + (size_t)(b * 2048 + q0 + cl) * 3072 + h * 64 + gp * 8;
  bf16x8 qf[2];
#pragma unroll
  for (int kk = 0; kk < 2; ++kk) {
    bf16x8 v = *(const bf16x8*)(Qp + kk * 32);
#pragma unroll
    for (int e = 0; e < 8; ++e) qf[kk][e] = (bf16_t)((float)v[e] * 0.125f);
  }
  const bf16_t* Kbase = qkv + (size_t)(b * 2048) * 3072 + 1024 + h * 64 + gp * 8;
  const bf16_t* Vbase = vT + (size_t)(bh * 64) * 2048 + gp * 8;

  f32x4 o[4];
#pragma unroll
  for (int c = 0; c < 4; ++c) o[c] = zero4();
  float mrun[4], lsum[4];
#pragma unroll
  for (int e = 0; e < 4; ++e) { mrun[e] = -1e30f; lsum[e] = 0.f; }

  int ntiles = (q0 + 47) >> 5;   // kv tiles of 32, causal-trimmed
  for (int tkv = 0; tkv < ntiles; ++tkv) {
    int kv0 = tkv * 32;
    // S = Q * K^T : B-operand col = kv index (cl), k = Dh
    f32x4 s0 = zero4(), s1 = zero4();
    {
      const bf16_t* Kp = Kbase + (size_t)(kv0 + cl) * 3072;
      bf16x8 k00 = *(const bf16x8*)(Kp);
      bf16x8 k01 = *(const bf16x8*)(Kp + 32);
      const bf16_t* Kp2 = Kp + (size_t)16 * 3072;
      bf16x8 k10 = *(const bf16x8*)(Kp2);
      bf16x8 k11 = *(const bf16x8*)(Kp2 + 32);
      s0 = MFMA16(qf[0], k00, s0);
      s0 = MFMA16(qf[1], k01, s0);
      s1 = MFMA16(qf[0], k10, s1);
      s1 = MFMA16(qf[1], k11, s1);
    }
    // mask + online softmax. S layout: row = gp*4+e (q), col = cl (kv, +16 for s1)
    float p0[4], p1[4], al[4];
#pragma unroll
    for (int e = 0; e < 4; ++e) {
      int row = q0 + gp * 4 + e;
      float v0 = s0[e], v1 = s1[e];
      if (kv0 + cl > row) v0 = -1e30f;
      if (kv0 + 16 + cl > row) v1 = -1e30f;
      float pm = fmaxf(v0, v1);
#pragma unroll
      for (int msk = 1; msk < 16; msk <<= 1) pm = fmaxf(pm, __shfl_xor(pm, msk));
      float mnew = fmaxf(mrun[e], pm);
      float a = __expf(mrun[e] - mnew);
      v0 = __expf(v0 - mnew);
      v1 = __expf(v1 - mnew);
      float rs = v0 + v1;
#pragma unroll
      for (int msk = 1; msk < 16; msk <<= 1) rs += __shfl_xor(rs, msk);
      lsum[e] = lsum[e] * a + rs;
      mrun[e] = mnew;
      p0[e] = v0; p1[e] = v1; al[e] = a;
    }
#pragma unroll
    for (int c = 0; c < 4; ++c)
#pragma unroll
      for (int e = 0; e < 4; ++e) o[c][e] *= al[e];
    // P -> LDS (acc layout) -> re-read as A-operand fragments
#pragma unroll
    for (int e = 0; e < 4; ++e) {
      P[(gp * 4 + e) * 32 + cl] = (bf16_t)p0[e];
      P[(gp * 4 + e) * 32 + 16 + cl] = (bf16_t)p1[e];
    }
    __syncthreads();
    bf16x8 pa = *(const bf16x8*)&P[cl * 32 + gp * 8];
#pragma unroll
    for (int c = 0; c < 4; ++c) {
      bf16x8 vf = *(const bf16x8*)(Vbase + (size_t)(c * 16 + cl) * 2048 + kv0);
      o[c] = MFMA16(pa, vf, o[c]);
    }
    __syncthreads();
  }

#pragma unroll
  for (int c = 0; c < 4; ++c)
#pragma unroll
    for (int e = 0; e < 4; ++e) {
      float val = o[c][e] / lsum[e];
      out[(size_t)(b * 2048 + q0 + gp * 4 + e) * 1024 + h * 64 + c * 16 + cl] = (bf16_t)val;
    }
}

// ---------------------------------------------------------------------------
extern "C" void kernel_launch(void* const* d_in, const int* in_sizes, int n_in,
                              void* d_out, int out_size, void* d_ws, size_t ws_size,
                              hipStream_t stream) {
  const float* x      = (const float*)d_in[0];   // (4,2048,1024)
  const float* w_qkv  = (const float*)d_in[1];   // (1024,3072)
  const float* w_proj = (const float*)d_in[2];   // (1024,1024)
  const float* b_proj = (const float*)d_in[3];   // (1024,)
  float* outp = (float*)d_out;

  char* ws = (char*)d_ws;
  bf16_t* xb     = (bf16_t*)(ws);                                      // 16 MiB
  bf16_t* wqkvT  = (bf16_t*)(ws + 16777216);                           // 6 MiB
  bf16_t* wprojT = (bf16_t*)(ws + 16777216 + 6291456);                 // 2 MiB
  bf16_t* qkv    = (bf16_t*)(ws + 16777216 + 6291456 + 2097152);       // 48 MiB
  bf16_t* vT     = (bf16_t*)(ws + 16777216 + 6291456 + 2097152 + 50331648);
  bf16_t* aout   = (bf16_t*)(ws + 16777216 + 6291456 + 2097152 + 50331648 + 16777216);

  k_cast<<<dim3(8192 * 1024 / (256 * 8)), 256, 0, stream>>>(x, xb);
  k_tcast<<<dim3(3072 / 64, 1024 / 64), 256, 0, stream>>>(w_qkv, wqkvT, 1024, 3072);
  k_tcast<<<dim3(1024 / 64, 1024 / 64), 256, 0, stream>>>(w_proj, wprojT, 1024, 1024);
  k_gemm_bt<true><<<dim3(3072 / 128, 8192 / 128), 256, 0, stream>>>(
      xb, wqkvT, (void*)qkv, nullptr, 8192, 3072, 1024);
  k_vtrans<<<dim3(2048 / 64, 64), 256, 0, stream>>>(qkv, vT);
  k_attn<<<dim3(128, 64), 64, 0, stream>>>(qkv, vT, aout);
  k_gemm_bt<false><<<dim3(1024 / 128, 8192 / 128), 256, 0, stream>>>(
      aout, wprojT, (void*)outp, b_proj, 8192, 1024, 1024);
}

// Round 2
// 417.238 us; speedup vs baseline: 1.2815x; 1.2815x over previous
//
#include <hip/hip_runtime.h>
#include <hip/hip_bf16.h>
#include <stdint.h>
#include <stddef.h>

typedef __bf16 bf16_t;
typedef __bf16 bf16x8 __attribute__((ext_vector_type(8)));
typedef float  f32x4  __attribute__((ext_vector_type(4)));

static __device__ __forceinline__ f32x4 zero4() { return (f32x4){0.f, 0.f, 0.f, 0.f}; }

#define MFMA16(a, b, c) __builtin_amdgcn_mfma_f32_16x16x32_bf16((a), (b), (c), 0, 0, 0)

#define GLOAD_LDS16(gptr, lptr)                                                        \
  __builtin_amdgcn_global_load_lds((const __attribute__((address_space(1))) void*)(gptr), \
                                   (__attribute__((address_space(3))) void*)(lptr), 16, 0, 0)

// ---------------- cast x fp32 -> bf16, 8 elems/thread ----------------
__global__ __launch_bounds__(256) void k_cast(const float* __restrict__ in,
                                              bf16_t* __restrict__ out) {
  size_t i = (size_t)blockIdx.x * 256 + threadIdx.x;
  const float4* p = (const float4*)in;
  float4 a = p[i * 2 + 0];
  float4 b = p[i * 2 + 1];
  bf16x8 v;
  v[0] = (bf16_t)a.x; v[1] = (bf16_t)a.y; v[2] = (bf16_t)a.z; v[3] = (bf16_t)a.w;
  v[4] = (bf16_t)b.x; v[5] = (bf16_t)b.y; v[6] = (bf16_t)b.z; v[7] = (bf16_t)b.w;
  *(bf16x8*)(out + i * 8) = v;
}

// ------------- transpose-cast: in fp32 [R][C] -> out bf16 [C][R] -------------
__global__ __launch_bounds__(256) void k_tcast(const float* __restrict__ in,
                                               bf16_t* __restrict__ out,
                                               int R, int C) {
  __shared__ bf16_t tile[64][72];
  int c0 = blockIdx.x * 64, r0 = blockIdx.y * 64;
  int t = threadIdx.x;
  int r = t >> 2, cc = (t & 3) * 16;
  const float* src = in + (size_t)(r0 + r) * C + c0 + cc;
#pragma unroll
  for (int q = 0; q < 4; ++q) {
    float4 v = *(const float4*)(src + q * 4);
    tile[r][cc + q * 4 + 0] = (bf16_t)v.x;
    tile[r][cc + q * 4 + 1] = (bf16_t)v.y;
    tile[r][cc + q * 4 + 2] = (bf16_t)v.z;
    tile[r][cc + q * 4 + 3] = (bf16_t)v.w;
  }
  __syncthreads();
  int c = t >> 2, rr = (t & 3) * 16;
  bf16x8 o0, o1;
#pragma unroll
  for (int j = 0; j < 8; ++j) { o0[j] = tile[rr + j][c]; o1[j] = tile[rr + 8 + j][c]; }
  bf16_t* dst = out + (size_t)(c0 + c) * R + r0 + rr;
  *(bf16x8*)dst = o0;
  *(bf16x8*)(dst + 8) = o1;
}

// ------- V transpose: qkv bf16 [8192][3072] -> vT bf16 [(bh*64+d)][2048] -------
__global__ __launch_bounds__(256) void k_vtrans(const bf16_t* __restrict__ qkv,
                                                bf16_t* __restrict__ vT) {
  __shared__ bf16_t tile[64][72];
  int t0 = blockIdx.x * 64, bh = blockIdx.y;
  int b = bh >> 4, h = bh & 15;
  int t = threadIdx.x;
  int tr = t >> 2, cc = (t & 3) * 16;
  const bf16_t* src = qkv + (size_t)(b * 2048 + t0 + tr) * 3072 + 2048 + h * 64 + cc;
  bf16x8 a0 = *(const bf16x8*)src;
  bf16x8 a1 = *(const bf16x8*)(src + 8);
#pragma unroll
  for (int j = 0; j < 8; ++j) { tile[tr][cc + j] = a0[j]; tile[tr][cc + 8 + j] = a1[j]; }
  __syncthreads();
  int d = t >> 2, tt = (t & 3) * 16;
  bf16x8 o0, o1;
#pragma unroll
  for (int j = 0; j < 8; ++j) { o0[j] = tile[tt + j][d]; o1[j] = tile[tt + 8 + j][d]; }
  bf16_t* dst = vT + (size_t)(bh * 64 + d) * 2048 + t0 + tt;
  *(bf16x8*)dst = o0;
  *(bf16x8*)(dst + 8) = o1;
}

// ------- K prep: qkv [8192][3072] -> kh bf16 [bh][2048][64], scaled by 1/8 -------
__global__ __launch_bounds__(256) void k_kprep(const bf16_t* __restrict__ qkv,
                                               bf16_t* __restrict__ kh) {
  int t0 = blockIdx.x * 64, bh = blockIdx.y;
  int b = bh >> 4, h = bh & 15;
  int t = threadIdx.x;
  int r = t >> 2, c = (t & 3) * 16;
  const bf16_t* src = qkv + (size_t)(b * 2048 + t0 + r) * 3072 + 1024 + h * 64 + c;
  bf16x8 a0 = *(const bf16x8*)src;
  bf16x8 a1 = *(const bf16x8*)(src + 8);
#pragma unroll
  for (int j = 0; j < 8; ++j) {
    a0[j] = (bf16_t)(0.125f * (float)a0[j]);
    a1[j] = (bf16_t)(0.125f * (float)a1[j]);
  }
  bf16_t* dst = kh + ((size_t)bh * 2048 + t0 + r) * 64 + c;
  *(bf16x8*)dst = a0;
  *(bf16x8*)(dst + 8) = a1;
}

// ---------------- GEMM: C[M][N] = A[M][K] * BT[N][K]^T (+bias) ----------------
template <bool BF16OUT>
__global__ __launch_bounds__(256) void k_gemm_bt(const bf16_t* __restrict__ A,
                                                 const bf16_t* __restrict__ BT,
                                                 void* __restrict__ Cout,
                                                 const float* __restrict__ bias,
                                                 int M, int N, int K) {
  __shared__ bf16_t sA[128 * 32];
  __shared__ bf16_t sB[128 * 32];
  int tid = threadIdx.x;
  int wid = tid >> 6, lane = tid & 63;
  int cl = lane & 15, gp = lane >> 4;
  int brow = blockIdx.y * 128, bcol = blockIdx.x * 128;
  int wr = wid >> 1, wc = wid & 1;
  f32x4 acc[4][4];
#pragma unroll
  for (int i = 0; i < 4; ++i)
#pragma unroll
    for (int j = 0; j < 4; ++j) acc[i][j] = zero4();

  int srow = tid >> 2;
  int sk = (tid & 3) * 8;
  const bf16_t* gA = A + (size_t)(brow + srow) * K + sk;
  const bf16_t* gB = BT + (size_t)(bcol + srow) * K + sk;
  char* lA = (char*)sA + wid * 1024;
  char* lB = (char*)sB + wid * 1024;

  for (int k0 = 0; k0 < K; k0 += 32) {
    __syncthreads();
    GLOAD_LDS16(gA + k0, lA);
    GLOAD_LDS16(gA + (size_t)64 * K + k0, lA + 4096);
    GLOAD_LDS16(gB + k0, lB);
    GLOAD_LDS16(gB + (size_t)64 * K + k0, lB + 4096);
    __syncthreads();
    bf16x8 af[4], bfr[4];
#pragma unroll
    for (int i = 0; i < 4; ++i)
      af[i] = *(const bf16x8*)&sA[(wr * 64 + i * 16 + cl) * 32 + gp * 8];
#pragma unroll
    for (int j = 0; j < 4; ++j)
      bfr[j] = *(const bf16x8*)&sB[(wc * 64 + j * 16 + cl) * 32 + gp * 8];
#pragma unroll
    for (int i = 0; i < 4; ++i)
#pragma unroll
      for (int j = 0; j < 4; ++j)
        acc[i][j] = MFMA16(af[i], bfr[j], acc[i][j]);
  }

#pragma unroll
  for (int i = 0; i < 4; ++i) {
    int row0 = brow + wr * 64 + i * 16 + gp * 4;
#pragma unroll
    for (int j = 0; j < 4; ++j) {
      int col = bcol + wc * 64 + j * 16 + cl;
#pragma unroll
      for (int e = 0; e < 4; ++e) {
        size_t idx = (size_t)(row0 + e) * N + col;
        if (BF16OUT)
          ((bf16_t*)Cout)[idx] = (bf16_t)acc[i][j][e];
        else
          ((float*)Cout)[idx] = acc[i][j][e] + bias[col];
      }
    }
  }
}

// ---------------- flash attention v2: 4 waves, QBLK=64, KVBLK=64 ----------------
// kh bf16 [bh][2048][64] (pre-scaled by 1/8); vT bf16 [(bh*64+d)][2048].
// LDS K/V tiles swizzled: linear(row, cb) holds global col bytes cb^((row&7)<<4).
__global__ __launch_bounds__(256) void k_attn2(const bf16_t* __restrict__ qkv,
                                               const bf16_t* __restrict__ kh,
                                               const bf16_t* __restrict__ vT,
                                               bf16_t* __restrict__ out) {
  __shared__ alignas(16) char sK[8192];   // [64 kv][128B d]
  __shared__ alignas(16) char sV[8192];   // [64 d][128B kv]
  __shared__ alignas(16) bf16_t sP[4][16 * 72];

  int bx = gridDim.x - 1 - blockIdx.x;    // big blocks first
  int bh = blockIdx.y;
  int b = bh >> 4, h = bh & 15;
  int tid = threadIdx.x, wid = tid >> 6, lane = tid & 63;
  int cl = lane & 15, gp = lane >> 4;
  int q0 = bx * 64, qw = q0 + wid * 16;

  // Q fragments: row=cl, k(d)=kk*32+gp*8+e (unscaled; kh carries the 1/8)
  const bf16_t* Qp = qkv + (size_t)(b * 2048 + qw + cl) * 3072 + h * 64 + gp * 8;
  bf16x8 qf0 = *(const bf16x8*)Qp;
  bf16x8 qf1 = *(const bf16x8*)(Qp + 32);

  // staging: thread covers LDS bytes tid*16 (+4096 round 1)
  int srow = tid >> 3;                 // 0..31
  int scb = (tid & 7) * 16;
  int swzcb = scb ^ ((srow & 7) << 4);
  const bf16_t* gK = kh + ((size_t)bh * 2048 + srow) * 64 + (swzcb >> 1);
  const bf16_t* gV = vT + ((size_t)(bh * 64) + srow) * 2048 + (swzcb >> 1);
  char* lK = sK + wid * 1024;
  char* lV = sV + wid * 1024;
  bf16_t* Pw = sP[wid];

  f32x4 o[4];
#pragma unroll
  for (int c = 0; c < 4; ++c) o[c] = zero4();
  float mrun[4], lsum[4];
#pragma unroll
  for (int e = 0; e < 4; ++e) { mrun[e] = -1e30f; lsum[e] = 0.f; }

  int swzK = (cl & 7) << 4;            // row swizzle for K-frag reads (row=j*16+cl)

  int ntiles = bx + 1;
  for (int t = 0; t < ntiles; ++t) {
    int kv0 = t * 64;
    __syncthreads();                   // prior PV reads done before overwrite
    GLOAD_LDS16(gK + (size_t)kv0 * 64, lK);
    GLOAD_LDS16(gK + (size_t)(kv0 + 32) * 64, lK + 4096);
    GLOAD_LDS16(gV + kv0, lV);
    GLOAD_LDS16(gV + kv0 + (size_t)32 * 2048, lV + 4096);
    __syncthreads();

    // S = Q K^T : per kv-subtile j, B-frag col=j*16+cl, k=kk*32+gp*8+e
    f32x4 s[4];
#pragma unroll
    for (int j = 0; j < 4; ++j) {
      const char* base = sK + (j * 16 + cl) * 128;
      bf16x8 k0 = *(const bf16x8*)(base + ((gp * 16) ^ swzK));
      bf16x8 k1 = *(const bf16x8*)(base + ((64 + gp * 16) ^ swzK));
      f32x4 acc = zero4();
      acc = MFMA16(qf0, k0, acc);
      acc = MFMA16(qf1, k1, acc);
      s[j] = acc;
    }

    // online softmax; S[j][e]: row = qw+gp*4+e, col = kv0+j*16+cl
    bool lastt = (t == bx);
    float a_[4];
#pragma unroll
    for (int e = 0; e < 4; ++e) {
      int row = qw + gp * 4 + e;
      float v0 = s[0][e], v1 = s[1][e], v2 = s[2][e], v3 = s[3][e];
      if (lastt) {
        if (kv0 + cl > row) v0 = -1e30f;
        if (kv0 + 16 + cl > row) v1 = -1e30f;
        if (kv0 + 32 + cl > row) v2 = -1e30f;
        if (kv0 + 48 + cl > row) v3 = -1e30f;
      }
      float pm = fmaxf(fmaxf(v0, v1), fmaxf(v2, v3));
#pragma unroll
      for (int msk = 1; msk < 16; msk <<= 1) pm = fmaxf(pm, __shfl_xor(pm, msk));
      float mnew = fmaxf(mrun[e], pm);
      float aa = __expf(mrun[e] - mnew);
      v0 = __expf(v0 - mnew); v1 = __expf(v1 - mnew);
      v2 = __expf(v2 - mnew); v3 = __expf(v3 - mnew);
      float rs = (v0 + v1) + (v2 + v3);
#pragma unroll
      for (int msk = 1; msk < 16; msk <<= 1) rs += __shfl_xor(rs, msk);
      lsum[e] = lsum[e] * aa + rs;
      mrun[e] = mnew;
      a_[e] = aa;
      int pr = (gp * 4 + e) * 72;
      Pw[pr + cl] = (bf16_t)v0;
      Pw[pr + 16 + cl] = (bf16_t)v1;
      Pw[pr + 32 + cl] = (bf16_t)v2;
      Pw[pr + 48 + cl] = (bf16_t)v3;
    }
#pragma unroll
    for (int c = 0; c < 4; ++c)
#pragma unroll
      for (int e = 0; e < 4; ++e) o[c][e] *= a_[e];

    asm volatile("" ::: "memory");     // keep P writes before P reads (same wave)
    bf16x8 pa0 = *(const bf16x8*)&Pw[cl * 72 + gp * 8];        // kv 0..31
    bf16x8 pa1 = *(const bf16x8*)&Pw[cl * 72 + 32 + gp * 8];   // kv 32..63
#pragma unroll
    for (int c = 0; c < 4; ++c) {
      const char* base = sV + (c * 16 + cl) * 128;
      bf16x8 v0 = *(const bf16x8*)(base + ((gp * 16) ^ swzK));
      bf16x8 v1 = *(const bf16x8*)(base + ((64 + gp * 16) ^ swzK));
      o[c] = MFMA16(pa0, v0, o[c]);
      o[c] = MFMA16(pa1, v1, o[c]);
    }
  }

#pragma unroll
  for (int e = 0; e < 4; ++e) {
    float inv = 1.0f / lsum[e];
    int row = qw + gp * 4 + e;
#pragma unroll
    for (int c = 0; c < 4; ++c)
      out[(size_t)(b * 2048 + row) * 1024 + h * 64 + c * 16 + cl] =
          (bf16_t)(o[c][e] * inv);
  }
}

// ---------------------------------------------------------------------------
extern "C" void kernel_launch(void* const* d_in, const int* in_sizes, int n_in,
                              void* d_out, int out_size, void* d_ws, size_t ws_size,
                              hipStream_t stream) {
  const float* x      = (const float*)d_in[0];
  const float* w_qkv  = (const float*)d_in[1];
  const float* w_proj = (const float*)d_in[2];
  const float* b_proj = (const float*)d_in[3];
  float* outp = (float*)d_out;

  char* ws = (char*)d_ws;
  bf16_t* xb     = (bf16_t*)(ws);                                      // 16 MiB
  bf16_t* wqkvT  = (bf16_t*)(ws + 16777216);                           // 6 MiB
  bf16_t* wprojT = (bf16_t*)(ws + 16777216 + 6291456);                 // 2 MiB
  bf16_t* qkv    = (bf16_t*)(ws + 16777216 + 6291456 + 2097152);       // 48 MiB
  bf16_t* vT     = (bf16_t*)(ws + 16777216 + 6291456 + 2097152 + 50331648);
  bf16_t* aout   = (bf16_t*)(ws + 16777216 + 6291456 + 2097152 + 50331648 + 16777216);
  bf16_t* kh     = xb;   // reuse xb region after GEMM1 consumed it (16 MiB)

  k_cast<<<dim3(8192 * 1024 / (256 * 8)), 256, 0, stream>>>(x, xb);
  k_tcast<<<dim3(3072 / 64, 1024 / 64), 256, 0, stream>>>(w_qkv, wqkvT, 1024, 3072);
  k_tcast<<<dim3(1024 / 64, 1024 / 64), 256, 0, stream>>>(w_proj, wprojT, 1024, 1024);
  k_gemm_bt<true><<<dim3(3072 / 128, 8192 / 128), 256, 0, stream>>>(
      xb, wqkvT, (void*)qkv, nullptr, 8192, 3072, 1024);
  k_kprep<<<dim3(32, 64), 256, 0, stream>>>(qkv, kh);
  k_vtrans<<<dim3(32, 64), 256, 0, stream>>>(qkv, vT);
  k_attn2<<<dim3(32, 64), 256, 0, stream>>>(qkv, kh, vT, aout);
  k_gemm_bt<false><<<dim3(1024 / 128, 8192 / 128), 256, 0, stream>>>(
      aout, wprojT, (void*)outp, b_proj, 8192, 1024, 1024);
}

// Round 3
// 362.150 us; speedup vs baseline: 1.4765x; 1.1521x over previous
//
#include <hip/hip_runtime.h>
#include <hip/hip_bf16.h>
#include <stdint.h>
#include <stddef.h>

typedef __bf16 bf16_t;
typedef __bf16 bf16x4 __attribute__((ext_vector_type(4)));
typedef __bf16 bf16x8 __attribute__((ext_vector_type(8)));
typedef float  f32x4  __attribute__((ext_vector_type(4)));

static __device__ __forceinline__ f32x4 zero4() { return (f32x4){0.f, 0.f, 0.f, 0.f}; }

#define MFMA16(a, b, c) __builtin_amdgcn_mfma_f32_16x16x32_bf16((a), (b), (c), 0, 0, 0)

#define GLOAD_LDS16(gptr, lptr)                                                        \
  __builtin_amdgcn_global_load_lds((const __attribute__((address_space(1))) void*)(gptr), \
                                   (__attribute__((address_space(3))) void*)(lptr), 16, 0, 0)

// ---------------- cast x fp32 -> bf16, 8 elems/thread ----------------
__global__ __launch_bounds__(256) void k_cast(const float* __restrict__ in,
                                              bf16_t* __restrict__ out) {
  size_t i = (size_t)blockIdx.x * 256 + threadIdx.x;
  const float4* p = (const float4*)in;
  float4 a = p[i * 2 + 0];
  float4 b = p[i * 2 + 1];
  bf16x8 v;
  v[0] = (bf16_t)a.x; v[1] = (bf16_t)a.y; v[2] = (bf16_t)a.z; v[3] = (bf16_t)a.w;
  v[4] = (bf16_t)b.x; v[5] = (bf16_t)b.y; v[6] = (bf16_t)b.z; v[7] = (bf16_t)b.w;
  *(bf16x8*)(out + i * 8) = v;
}

// ------------- transpose-cast: in fp32 [R][C] -> out bf16 [C][R] -------------
__global__ __launch_bounds__(256) void k_tcast(const float* __restrict__ in,
                                               bf16_t* __restrict__ out,
                                               int R, int C) {
  __shared__ bf16_t tile[64][72];
  int c0 = blockIdx.x * 64, r0 = blockIdx.y * 64;
  int t = threadIdx.x;
  int r = t >> 2, cc = (t & 3) * 16;
  const float* src = in + (size_t)(r0 + r) * C + c0 + cc;
#pragma unroll
  for (int q = 0; q < 4; ++q) {
    float4 v = *(const float4*)(src + q * 4);
    tile[r][cc + q * 4 + 0] = (bf16_t)v.x;
    tile[r][cc + q * 4 + 1] = (bf16_t)v.y;
    tile[r][cc + q * 4 + 2] = (bf16_t)v.z;
    tile[r][cc + q * 4 + 3] = (bf16_t)v.w;
  }
  __syncthreads();
  int c = t >> 2, rr = (t & 3) * 16;
  bf16x8 o0, o1;
#pragma unroll
  for (int j = 0; j < 8; ++j) { o0[j] = tile[rr + j][c]; o1[j] = tile[rr + 8 + j][c]; }
  bf16_t* dst = out + (size_t)(c0 + c) * R + r0 + rr;
  *(bf16x8*)dst = o0;
  *(bf16x8*)(dst + 8) = o1;
}

// ------- V transpose: qkv bf16 [8192][3072] -> vT bf16 [(bh*64+d)][2048] -------
__global__ __launch_bounds__(256) void k_vtrans(const bf16_t* __restrict__ qkv,
                                                bf16_t* __restrict__ vT) {
  __shared__ bf16_t tile[64][72];
  int t0 = blockIdx.x * 64, bh = blockIdx.y;
  int b = bh >> 4, h = bh & 15;
  int t = threadIdx.x;
  int tr = t >> 2, cc = (t & 3) * 16;
  const bf16_t* src = qkv + (size_t)(b * 2048 + t0 + tr) * 3072 + 2048 + h * 64 + cc;
  bf16x8 a0 = *(const bf16x8*)src;
  bf16x8 a1 = *(const bf16x8*)(src + 8);
#pragma unroll
  for (int j = 0; j < 8; ++j) { tile[tr][cc + j] = a0[j]; tile[tr][cc + 8 + j] = a1[j]; }
  __syncthreads();
  int d = t >> 2, tt = (t & 3) * 16;
  bf16x8 o0, o1;
#pragma unroll
  for (int j = 0; j < 8; ++j) { o0[j] = tile[tt + j][d]; o1[j] = tile[tt + 8 + j][d]; }
  bf16_t* dst = vT + (size_t)(bh * 64 + d) * 2048 + t0 + tt;
  *(bf16x8*)dst = o0;
  *(bf16x8*)(dst + 8) = o1;
}

// ------- K prep: qkv [8192][3072] -> kh bf16 [bh][2048][64], scaled by 1/8 -------
__global__ __launch_bounds__(256) void k_kprep(const bf16_t* __restrict__ qkv,
                                               bf16_t* __restrict__ kh) {
  int t0 = blockIdx.x * 64, bh = blockIdx.y;
  int b = bh >> 4, h = bh & 15;
  int t = threadIdx.x;
  int r = t >> 2, c = (t & 3) * 16;
  const bf16_t* src = qkv + (size_t)(b * 2048 + t0 + r) * 3072 + 1024 + h * 64 + c;
  bf16x8 a0 = *(const bf16x8*)src;
  bf16x8 a1 = *(const bf16x8*)(src + 8);
#pragma unroll
  for (int j = 0; j < 8; ++j) {
    a0[j] = (bf16_t)(0.125f * (float)a0[j]);
    a1[j] = (bf16_t)(0.125f * (float)a1[j]);
  }
  bf16_t* dst = kh + ((size_t)bh * 2048 + t0 + r) * 64 + c;
  *(bf16x8*)dst = a0;
  *(bf16x8*)(dst + 8) = a1;
}

// ---------------- GEMM: C[M][N] = A[M][K] * BT[N][K]^T (+bias) ----------------
template <bool BF16OUT>
__global__ __launch_bounds__(256) void k_gemm_bt(const bf16_t* __restrict__ A,
                                                 const bf16_t* __restrict__ BT,
                                                 void* __restrict__ Cout,
                                                 const float* __restrict__ bias,
                                                 int M, int N, int K) {
  __shared__ bf16_t sA[128 * 32];
  __shared__ bf16_t sB[128 * 32];
  int tid = threadIdx.x;
  int wid = tid >> 6, lane = tid & 63;
  int cl = lane & 15, gp = lane >> 4;
  int brow = blockIdx.y * 128, bcol = blockIdx.x * 128;
  int wr = wid >> 1, wc = wid & 1;
  f32x4 acc[4][4];
#pragma unroll
  for (int i = 0; i < 4; ++i)
#pragma unroll
    for (int j = 0; j < 4; ++j) acc[i][j] = zero4();

  int srow = tid >> 2;
  int sk = (tid & 3) * 8;
  const bf16_t* gA = A + (size_t)(brow + srow) * K + sk;
  const bf16_t* gB = BT + (size_t)(bcol + srow) * K + sk;
  char* lA = (char*)sA + wid * 1024;
  char* lB = (char*)sB + wid * 1024;

  for (int k0 = 0; k0 < K; k0 += 32) {
    __syncthreads();
    GLOAD_LDS16(gA + k0, lA);
    GLOAD_LDS16(gA + (size_t)64 * K + k0, lA + 4096);
    GLOAD_LDS16(gB + k0, lB);
    GLOAD_LDS16(gB + (size_t)64 * K + k0, lB + 4096);
    __syncthreads();
    bf16x8 af[4], bfr[4];
#pragma unroll
    for (int i = 0; i < 4; ++i)
      af[i] = *(const bf16x8*)&sA[(wr * 64 + i * 16 + cl) * 32 + gp * 8];
#pragma unroll
    for (int j = 0; j < 4; ++j)
      bfr[j] = *(const bf16x8*)&sB[(wc * 64 + j * 16 + cl) * 32 + gp * 8];
#pragma unroll
    for (int i = 0; i < 4; ++i)
#pragma unroll
      for (int j = 0; j < 4; ++j)
        acc[i][j] = MFMA16(af[i], bfr[j], acc[i][j]);
  }

#pragma unroll
  for (int i = 0; i < 4; ++i) {
    int row0 = brow + wr * 64 + i * 16 + gp * 4;
#pragma unroll
    for (int j = 0; j < 4; ++j) {
      int col = bcol + wc * 64 + j * 16 + cl;
#pragma unroll
      for (int e = 0; e < 4; ++e) {
        size_t idx = (size_t)(row0 + e) * N + col;
        if (BF16OUT)
          ((bf16_t*)Cout)[idx] = (bf16_t)acc[i][j][e];
        else
          ((float*)Cout)[idx] = acc[i][j][e] + bias[col];
      }
    }
  }
}

// ---- flash attention v3: 4 waves, QBLK=128 (2 m-blocks/wave), KVBLK=64, dbuf ----
// Swapped QK^T (S^T = K·Q^T) => in-register row softmax; prefetch t+1 during t.
__global__ __launch_bounds__(256) void k_attn3(const bf16_t* __restrict__ qkv,
                                               const bf16_t* __restrict__ kh,
                                               const bf16_t* __restrict__ vT,
                                               bf16_t* __restrict__ out) {
  __shared__ alignas(16) char sK[2][8192];   // [64 kv][128B d], XOR-swizzled
  __shared__ alignas(16) char sV[2][8192];   // [64 d][128B kv], XOR-swizzled
  __shared__ alignas(16) char sP[4][2][2048];// per wave, per m: [16 q][128B kv]

  int bx = gridDim.x - 1 - blockIdx.x;       // big blocks first
  int bh = blockIdx.y;
  int b = bh >> 4, h = bh & 15;
  int tid = threadIdx.x, wid = tid >> 6, lane = tid & 63;
  int cl = lane & 15, gp = lane >> 4;
  int q0 = bx * 128;
  int qw0 = q0 + wid * 16;
  int qw1 = q0 + 64 + wid * 16;

  // Q fragments (B-operand): col=cl(q), k(d)=gp*8+e. kh carries the 1/8 scale.
  bf16x8 qf00, qf01, qf10, qf11;
  {
    const bf16_t* Qp = qkv + (size_t)(b * 2048 + qw0 + cl) * 3072 + h * 64 + gp * 8;
    qf00 = *(const bf16x8*)Qp;
    qf01 = *(const bf16x8*)(Qp + 32);
    const bf16_t* Qp1 = qkv + (size_t)(b * 2048 + qw1 + cl) * 3072 + h * 64 + gp * 8;
    qf10 = *(const bf16x8*)Qp1;
    qf11 = *(const bf16x8*)(Qp1 + 32);
  }

  int srow = tid >> 3;
  int swzcb = ((tid & 7) * 16) ^ ((srow & 7) << 4);
  const bf16_t* gK = kh + ((size_t)bh * 2048 + srow) * 64 + (swzcb >> 1);
  const bf16_t* gV = vT + ((size_t)(bh * 64) + srow) * 2048 + (swzcb >> 1);

  f32x4 o0[4], o1[4];
#pragma unroll
  for (int c = 0; c < 4; ++c) { o0[c] = zero4(); o1[c] = zero4(); }
  float mrun0 = -1e30f, mrun1 = -1e30f, lsum0 = 0.f, lsum1 = 0.f;

  int swz = (cl & 7) << 4;
  int nt = 2 * (bx + 1);

  // prologue: stage tile 0 into buf 0
  {
    char* lK = sK[0] + wid * 1024;
    char* lV = sV[0] + wid * 1024;
    GLOAD_LDS16(gK, lK);
    GLOAD_LDS16(gK + 32 * 64, lK + 4096);
    GLOAD_LDS16(gV, lV);
    GLOAD_LDS16(gV + (size_t)32 * 2048, lV + 4096);
  }
  asm volatile("s_waitcnt vmcnt(0)");
  __syncthreads();

  for (int t = 0; t < nt; ++t) {
    int cur = t & 1;
    int kv0 = t * 64;
    if (t + 1 < nt) {                       // prefetch next tile into other buffer
      int kv1 = kv0 + 64;
      char* lK = sK[cur ^ 1] + wid * 1024;
      char* lV = sV[cur ^ 1] + wid * 1024;
      GLOAD_LDS16(gK + (size_t)kv1 * 64, lK);
      GLOAD_LDS16(gK + (size_t)(kv1 + 32) * 64, lK + 4096);
      GLOAD_LDS16(gV + kv1, lV);
      GLOAD_LDS16(gV + kv1 + (size_t)32 * 2048, lV + 4096);
    }
    const char* bK = sK[cur];
    const char* bV = sV[cur];
    bool act0 = (kv0 <= qw0 + 15);          // wave-uniform; m1 is always active

    // S^T = K·Q^T per kv-subtile j: A=K(row=kv), B=Q(col=q); shared K reads
    f32x4 s0[4], s1[4];
#pragma unroll
    for (int j = 0; j < 4; ++j) {
      const char* base = bK + (j * 16 + cl) * 128;
      bf16x8 k0 = *(const bf16x8*)(base + ((gp * 16) ^ swz));
      bf16x8 k1 = *(const bf16x8*)(base + ((64 + gp * 16) ^ swz));
      if (act0) {
        f32x4 a = zero4();
        a = MFMA16(k0, qf00, a);
        a = MFMA16(k1, qf01, a);
        s0[j] = a;
      }
      f32x4 a1 = zero4();
      a1 = MFMA16(k0, qf10, a1);
      a1 = MFMA16(k1, qf11, a1);
      s1[j] = a1;
    }

    // in-register softmax per m-block. s[j][e]: q=cl, kv=kv0+j*16+gp*4+e
    char* Pw0 = sP[wid][0];
    char* Pw1 = sP[wid][1];
    if (act0) {
      int qrow = qw0 + cl;
      if (kv0 + 63 > qw0) {
#pragma unroll
        for (int j = 0; j < 4; ++j)
#pragma unroll
          for (int e = 0; e < 4; ++e)
            if (kv0 + j * 16 + gp * 4 + e > qrow) s0[j][e] = -1e30f;
      }
      float pm = -1e30f;
#pragma unroll
      for (int j = 0; j < 4; ++j)
#pragma unroll
        for (int e = 0; e < 4; ++e) pm = fmaxf(pm, s0[j][e]);
      pm = fmaxf(pm, __shfl_xor(pm, 16));
      pm = fmaxf(pm, __shfl_xor(pm, 32));
      float mold = mrun0, mnew = mold;
      if (!__all(pm <= mold + 8.f)) {       // defer-max (T13)
        mnew = fmaxf(mold, pm);
        float aa = __expf(mold - mnew);
        mrun0 = mnew;
        lsum0 *= aa;
#pragma unroll
        for (int e = 0; e < 4; ++e) {
          float ae = __shfl(aa, gp * 4 + e);
#pragma unroll
          for (int c = 0; c < 4; ++c) o0[c][e] *= ae;
        }
      }
      float rs = 0.f;
#pragma unroll
      for (int j = 0; j < 4; ++j) {
        bf16x4 pw;
#pragma unroll
        for (int e = 0; e < 4; ++e) {
          float p = __expf(s0[j][e] - mnew);
          rs += p;
          pw[e] = (bf16_t)p;
        }
        *(bf16x4*)(Pw0 + cl * 128 + ((j * 32 + gp * 8) ^ swz)) = pw;
      }
      rs += __shfl_xor(rs, 16);
      rs += __shfl_xor(rs, 32);
      lsum0 += rs;
    }
    {
      int qrow = qw1 + cl;
      if (kv0 + 63 > qw1) {
#pragma unroll
        for (int j = 0; j < 4; ++j)
#pragma unroll
          for (int e = 0; e < 4; ++e)
            if (kv0 + j * 16 + gp * 4 + e > qrow) s1[j][e] = -1e30f;
      }
      float pm = -1e30f;
#pragma unroll
      for (int j = 0; j < 4; ++j)
#pragma unroll
        for (int e = 0; e < 4; ++e) pm = fmaxf(pm, s1[j][e]);
      pm = fmaxf(pm, __shfl_xor(pm, 16));
      pm = fmaxf(pm, __shfl_xor(pm, 32));
      float mold = mrun1, mnew = mold;
      if (!__all(pm <= mold + 8.f)) {
        mnew = fmaxf(mold, pm);
        float aa = __expf(mold - mnew);
        mrun1 = mnew;
        lsum1 *= aa;
#pragma unroll
        for (int e = 0; e < 4; ++e) {
          float ae = __shfl(aa, gp * 4 + e);
#pragma unroll
          for (int c = 0; c < 4; ++c) o1[c][e] *= ae;
        }
      }
      float rs = 0.f;
#pragma unroll
      for (int j = 0; j < 4; ++j) {
        bf16x4 pw;
#pragma unroll
        for (int e = 0; e < 4; ++e) {
          float p = __expf(s1[j][e] - mnew);
          rs += p;
          pw[e] = (bf16_t)p;
        }
        *(bf16x4*)(Pw1 + cl * 128 + ((j * 32 + gp * 8) ^ swz)) = pw;
      }
      rs += __shfl_xor(rs, 16);
      rs += __shfl_xor(rs, 32);
      lsum1 += rs;
    }

    asm volatile("" ::: "memory");          // P writes before P reads (same wave)
    bf16x8 pa00, pa01, pa10, pa11;
    if (act0) {
      pa00 = *(const bf16x8*)(Pw0 + cl * 128 + ((gp * 16) ^ swz));
      pa01 = *(const bf16x8*)(Pw0 + cl * 128 + ((64 + gp * 16) ^ swz));
    }
    pa10 = *(const bf16x8*)(Pw1 + cl * 128 + ((gp * 16) ^ swz));
    pa11 = *(const bf16x8*)(Pw1 + cl * 128 + ((64 + gp * 16) ^ swz));

    __builtin_amdgcn_s_setprio(1);
#pragma unroll
    for (int c = 0; c < 4; ++c) {
      const char* base = bV + (c * 16 + cl) * 128;
      bf16x8 v0 = *(const bf16x8*)(base + ((gp * 16) ^ swz));
      bf16x8 v1 = *(const bf16x8*)(base + ((64 + gp * 16) ^ swz));
      if (act0) {
        o0[c] = MFMA16(pa00, v0, o0[c]);
        o0[c] = MFMA16(pa01, v1, o0[c]);
      }
      o1[c] = MFMA16(pa10, v0, o1[c]);
      o1[c] = MFMA16(pa11, v1, o1[c]);
    }
    __builtin_amdgcn_s_setprio(0);

    asm volatile("s_waitcnt vmcnt(0)");     // prefetched tile landed
    __syncthreads();
  }

  // epilogue: redistribute lsum (q=cl domain -> q=gp*4+e domain) and store
#pragma unroll
  for (int e = 0; e < 4; ++e) {
    float inv0 = 1.0f / __shfl(lsum0, gp * 4 + e);
    float inv1 = 1.0f / __shfl(lsum1, gp * 4 + e);
    int r0 = qw0 + gp * 4 + e;
    int r1 = qw1 + gp * 4 + e;
#pragma unroll
    for (int c = 0; c < 4; ++c) {
      out[(size_t)(b * 2048 + r0) * 1024 + h * 64 + c * 16 + cl] = (bf16_t)(o0[c][e] * inv0);
      out[(size_t)(b * 2048 + r1) * 1024 + h * 64 + c * 16 + cl] = (bf16_t)(o1[c][e] * inv1);
    }
  }
}

// ---------------------------------------------------------------------------
extern "C" void kernel_launch(void* const* d_in, const int* in_sizes, int n_in,
                              void* d_out, int out_size, void* d_ws, size_t ws_size,
                              hipStream_t stream) {
  const float* x      = (const float*)d_in[0];
  const float* w_qkv  = (const float*)d_in[1];
  const float* w_proj = (const float*)d_in[2];
  const float* b_proj = (const float*)d_in[3];
  float* outp = (float*)d_out;

  char* ws = (char*)d_ws;
  bf16_t* xb     = (bf16_t*)(ws);                                      // 16 MiB
  bf16_t* wqkvT  = (bf16_t*)(ws + 16777216);                           // 6 MiB
  bf16_t* wprojT = (bf16_t*)(ws + 16777216 + 6291456);                 // 2 MiB
  bf16_t* qkv    = (bf16_t*)(ws + 16777216 + 6291456 + 2097152);       // 48 MiB
  bf16_t* vT     = (bf16_t*)(ws + 16777216 + 6291456 + 2097152 + 50331648);
  bf16_t* aout   = (bf16_t*)(ws + 16777216 + 6291456 + 2097152 + 50331648 + 16777216);
  bf16_t* kh     = xb;   // reuse xb region after GEMM1 consumed it

  k_cast<<<dim3(8192 * 1024 / (256 * 8)), 256, 0, stream>>>(x, xb);
  k_tcast<<<dim3(3072 / 64, 1024 / 64), 256, 0, stream>>>(w_qkv, wqkvT, 1024, 3072);
  k_tcast<<<dim3(1024 / 64, 1024 / 64), 256, 0, stream>>>(w_proj, wprojT, 1024, 1024);
  k_gemm_bt<true><<<dim3(3072 / 128, 8192 / 128), 256, 0, stream>>>(
      xb, wqkvT, (void*)qkv, nullptr, 8192, 3072, 1024);
  k_kprep<<<dim3(32, 64), 256, 0, stream>>>(qkv, kh);
  k_vtrans<<<dim3(32, 64), 256, 0, stream>>>(qkv, vT);
  k_attn3<<<dim3(16, 64), 256, 0, stream>>>(qkv, kh, vT, aout);
  k_gemm_bt<false><<<dim3(1024 / 128, 8192 / 128), 256, 0, stream>>>(
      aout, wprojT, (void*)outp, b_proj, 8192, 1024, 1024);
}

// Round 4
// 356.825 us; speedup vs baseline: 1.4985x; 1.0149x over previous
//
#include <hip/hip_runtime.h>
#include <hip/hip_bf16.h>
#include <stdint.h>
#include <stddef.h>

typedef __bf16 bf16_t;
typedef __bf16 bf16x4 __attribute__((ext_vector_type(4)));
typedef __bf16 bf16x8 __attribute__((ext_vector_type(8)));
typedef float  f32x4  __attribute__((ext_vector_type(4)));

static __device__ __forceinline__ f32x4 zero4() { return (f32x4){0.f, 0.f, 0.f, 0.f}; }

#define MFMA16(a, b, c) __builtin_amdgcn_mfma_f32_16x16x32_bf16((a), (b), (c), 0, 0, 0)

#define GLOAD_LDS16(gptr, lptr)                                                        \
  __builtin_amdgcn_global_load_lds((const __attribute__((address_space(1))) void*)(gptr), \
                                   (__attribute__((address_space(3))) void*)(lptr), 16, 0, 0)

// ---------------- cast x fp32 -> bf16, 8 elems/thread ----------------
__global__ __launch_bounds__(256) void k_cast(const float* __restrict__ in,
                                              bf16_t* __restrict__ out) {
  size_t i = (size_t)blockIdx.x * 256 + threadIdx.x;
  const float4* p = (const float4*)in;
  float4 a = p[i * 2 + 0];
  float4 b = p[i * 2 + 1];
  bf16x8 v;
  v[0] = (bf16_t)a.x; v[1] = (bf16_t)a.y; v[2] = (bf16_t)a.z; v[3] = (bf16_t)a.w;
  v[4] = (bf16_t)b.x; v[5] = (bf16_t)b.y; v[6] = (bf16_t)b.z; v[7] = (bf16_t)b.w;
  *(bf16x8*)(out + i * 8) = v;
}

// ------------- transpose-cast: in fp32 [R][C] -> out bf16 [C][R] -------------
__global__ __launch_bounds__(256) void k_tcast(const float* __restrict__ in,
                                               bf16_t* __restrict__ out,
                                               int R, int C) {
  __shared__ bf16_t tile[64][72];
  int c0 = blockIdx.x * 64, r0 = blockIdx.y * 64;
  int t = threadIdx.x;
  int r = t >> 2, cc = (t & 3) * 16;
  const float* src = in + (size_t)(r0 + r) * C + c0 + cc;
#pragma unroll
  for (int q = 0; q < 4; ++q) {
    float4 v = *(const float4*)(src + q * 4);
    tile[r][cc + q * 4 + 0] = (bf16_t)v.x;
    tile[r][cc + q * 4 + 1] = (bf16_t)v.y;
    tile[r][cc + q * 4 + 2] = (bf16_t)v.z;
    tile[r][cc + q * 4 + 3] = (bf16_t)v.w;
  }
  __syncthreads();
  int c = t >> 2, rr = (t & 3) * 16;
  bf16x8 o0, o1;
#pragma unroll
  for (int j = 0; j < 8; ++j) { o0[j] = tile[rr + j][c]; o1[j] = tile[rr + 8 + j][c]; }
  bf16_t* dst = out + (size_t)(c0 + c) * R + r0 + rr;
  *(bf16x8*)dst = o0;
  *(bf16x8*)(dst + 8) = o1;
}

// ------- V transpose: qkv bf16 [8192][3072] -> vT bf16 [(bh*64+d)][2048] -------
__global__ __launch_bounds__(256) void k_vtrans(const bf16_t* __restrict__ qkv,
                                                bf16_t* __restrict__ vT) {
  __shared__ bf16_t tile[64][72];
  int t0 = blockIdx.x * 64, bh = blockIdx.y;
  int b = bh >> 4, h = bh & 15;
  int t = threadIdx.x;
  int tr = t >> 2, cc = (t & 3) * 16;
  const bf16_t* src = qkv + (size_t)(b * 2048 + t0 + tr) * 3072 + 2048 + h * 64 + cc;
  bf16x8 a0 = *(const bf16x8*)src;
  bf16x8 a1 = *(const bf16x8*)(src + 8);
#pragma unroll
  for (int j = 0; j < 8; ++j) { tile[tr][cc + j] = a0[j]; tile[tr][cc + 8 + j] = a1[j]; }
  __syncthreads();
  int d = t >> 2, tt = (t & 3) * 16;
  bf16x8 o0, o1;
#pragma unroll
  for (int j = 0; j < 8; ++j) { o0[j] = tile[tt + j][d]; o1[j] = tile[tt + 8 + j][d]; }
  bf16_t* dst = vT + (size_t)(bh * 64 + d) * 2048 + t0 + tt;
  *(bf16x8*)dst = o0;
  *(bf16x8*)(dst + 8) = o1;
}

// ------- K prep: qkv [8192][3072] -> kh bf16 [bh][2048][64], scaled by 1/8 -------
__global__ __launch_bounds__(256) void k_kprep(const bf16_t* __restrict__ qkv,
                                               bf16_t* __restrict__ kh) {
  int t0 = blockIdx.x * 64, bh = blockIdx.y;
  int b = bh >> 4, h = bh & 15;
  int t = threadIdx.x;
  int r = t >> 2, c = (t & 3) * 16;
  const bf16_t* src = qkv + (size_t)(b * 2048 + t0 + r) * 3072 + 1024 + h * 64 + c;
  bf16x8 a0 = *(const bf16x8*)src;
  bf16x8 a1 = *(const bf16x8*)(src + 8);
#pragma unroll
  for (int j = 0; j < 8; ++j) {
    a0[j] = (bf16_t)(0.125f * (float)a0[j]);
    a1[j] = (bf16_t)(0.125f * (float)a1[j]);
  }
  bf16_t* dst = kh + ((size_t)bh * 2048 + t0 + r) * 64 + c;
  *(bf16x8*)dst = a0;
  *(bf16x8*)(dst + 8) = a1;
}

// ---------------- GEMM: C[M][N] = A[M][K] * BT[N][K]^T (+bias) ----------------
template <bool BF16OUT>
__global__ __launch_bounds__(256) void k_gemm_bt(const bf16_t* __restrict__ A,
                                                 const bf16_t* __restrict__ BT,
                                                 void* __restrict__ Cout,
                                                 const float* __restrict__ bias,
                                                 int M, int N, int K) {
  __shared__ bf16_t sA[128 * 32];
  __shared__ bf16_t sB[128 * 32];
  int tid = threadIdx.x;
  int wid = tid >> 6, lane = tid & 63;
  int cl = lane & 15, gp = lane >> 4;
  // bijective XCD swizzle (nwg % 8 == 0 for both GEMMs)
  int nwg = gridDim.x * gridDim.y;
  int flat = blockIdx.y * gridDim.x + blockIdx.x;
  int cpx = nwg >> 3;
  int swzid = (flat & 7) * cpx + (flat >> 3);
  int brow = (swzid / gridDim.x) * 128, bcol = (swzid % gridDim.x) * 128;
  int wr = wid >> 1, wc = wid & 1;
  f32x4 acc[4][4];
#pragma unroll
  for (int i = 0; i < 4; ++i)
#pragma unroll
    for (int j = 0; j < 4; ++j) acc[i][j] = zero4();

  int srow = tid >> 2;
  int sk = (tid & 3) * 8;
  const bf16_t* gA = A + (size_t)(brow + srow) * K + sk;
  const bf16_t* gB = BT + (size_t)(bcol + srow) * K + sk;
  char* lA = (char*)sA + wid * 1024;
  char* lB = (char*)sB + wid * 1024;

  for (int k0 = 0; k0 < K; k0 += 32) {
    __syncthreads();
    GLOAD_LDS16(gA + k0, lA);
    GLOAD_LDS16(gA + (size_t)64 * K + k0, lA + 4096);
    GLOAD_LDS16(gB + k0, lB);
    GLOAD_LDS16(gB + (size_t)64 * K + k0, lB + 4096);
    __syncthreads();
    bf16x8 af[4], bfr[4];
#pragma unroll
    for (int i = 0; i < 4; ++i)
      af[i] = *(const bf16x8*)&sA[(wr * 64 + i * 16 + cl) * 32 + gp * 8];
#pragma unroll
    for (int j = 0; j < 4; ++j)
      bfr[j] = *(const bf16x8*)&sB[(wc * 64 + j * 16 + cl) * 32 + gp * 8];
#pragma unroll
    for (int i = 0; i < 4; ++i)
#pragma unroll
      for (int j = 0; j < 4; ++j)
        acc[i][j] = MFMA16(af[i], bfr[j], acc[i][j]);
  }

#pragma unroll
  for (int i = 0; i < 4; ++i) {
    int row0 = brow + wr * 64 + i * 16 + gp * 4;
#pragma unroll
    for (int j = 0; j < 4; ++j) {
      int col = bcol + wc * 64 + j * 16 + cl;
#pragma unroll
      for (int e = 0; e < 4; ++e) {
        size_t idx = (size_t)(row0 + e) * N + col;
        if (BF16OUT)
          ((bf16_t*)Cout)[idx] = (bf16_t)acc[i][j][e];
        else
          ((float*)Cout)[idx] = acc[i][j][e] + bias[col];
      }
    }
  }
}

// ---------------- attention v4 helpers ----------------
static __device__ __forceinline__ void softmax_m(f32x4 (&s)[4], f32x4 (&o)[4],
                                                 float& mrun, float& lsum, char* Pw,
                                                 int kv0, int qw, int swz, int cl, int gp) {
  int qrow = qw + cl;
  if (kv0 + 63 > qw) {
#pragma unroll
    for (int jj = 0; jj < 4; ++jj)
#pragma unroll
      for (int e = 0; e < 4; ++e)
        if (kv0 + jj * 16 + gp * 4 + e > qrow) s[jj][e] = -1e30f;
  }
  float pm = -1e30f;
#pragma unroll
  for (int jj = 0; jj < 4; ++jj)
#pragma unroll
    for (int e = 0; e < 4; ++e) pm = fmaxf(pm, s[jj][e]);
  pm = fmaxf(pm, __shfl_xor(pm, 16));
  pm = fmaxf(pm, __shfl_xor(pm, 32));
  float mold = mrun, mnew = mold;
  if (!__all(pm <= mold + 8.f)) {           // defer-max (T13)
    mnew = fmaxf(mold, pm);
    float aa = __expf(mold - mnew);
    mrun = mnew;
    lsum *= aa;
#pragma unroll
    for (int e = 0; e < 4; ++e) {
      float ae = __shfl(aa, gp * 4 + e);
#pragma unroll
      for (int c = 0; c < 4; ++c) o[c][e] *= ae;
    }
  }
  float rs = 0.f;
#pragma unroll
  for (int jj = 0; jj < 4; ++jj) {
    bf16x4 pw;
#pragma unroll
    for (int e = 0; e < 4; ++e) {
      float p = __expf(s[jj][e] - mnew);
      rs += p;
      pw[e] = (bf16_t)p;
    }
    *(bf16x4*)(Pw + cl * 128 + ((jj * 32 + gp * 8) ^ swz)) = pw;
  }
  rs += __shfl_xor(rs, 16);
  rs += __shfl_xor(rs, 32);
  lsum += rs;
}

// one q-tile pass (2 m-blocks) over the current KV tile
static __device__ __forceinline__ void attn_pass(const char* __restrict__ bK,
                                                 const char* __restrict__ bV,
                                                 char* __restrict__ Pw0,
                                                 char* __restrict__ Pw1,
                                                 const bf16x8 (&qf)[2][2],
                                                 f32x4 (&o0)[4], f32x4 (&o1)[4],
                                                 float (&mrun)[2], float (&lsum)[2],
                                                 int kv0, int qw0, int qw1,
                                                 int swz, int cl, int gp, bool act0) {
  f32x4 s0[4], s1[4];
#pragma unroll
  for (int jj = 0; jj < 4; ++jj) {
    const char* base = bK + (jj * 16 + cl) * 128;
    bf16x8 k0 = *(const bf16x8*)(base + ((gp * 16) ^ swz));
    bf16x8 k1 = *(const bf16x8*)(base + ((64 + gp * 16) ^ swz));
    if (act0) {
      f32x4 a = zero4();
      a = MFMA16(k0, qf[0][0], a);
      a = MFMA16(k1, qf[0][1], a);
      s0[jj] = a;
    }
    f32x4 a1 = zero4();
    a1 = MFMA16(k0, qf[1][0], a1);
    a1 = MFMA16(k1, qf[1][1], a1);
    s1[jj] = a1;
  }
  if (act0) softmax_m(s0, o0, mrun[0], lsum[0], Pw0, kv0, qw0, swz, cl, gp);
  softmax_m(s1, o1, mrun[1], lsum[1], Pw1, kv0, qw1, swz, cl, gp);

  asm volatile("" ::: "memory");            // P writes before P reads (same wave)
  bf16x8 pa00, pa01, pa10, pa11;
  if (act0) {
    pa00 = *(const bf16x8*)(Pw0 + cl * 128 + ((gp * 16) ^ swz));
    pa01 = *(const bf16x8*)(Pw0 + cl * 128 + ((64 + gp * 16) ^ swz));
  }
  pa10 = *(const bf16x8*)(Pw1 + cl * 128 + ((gp * 16) ^ swz));
  pa11 = *(const bf16x8*)(Pw1 + cl * 128 + ((64 + gp * 16) ^ swz));

  __builtin_amdgcn_s_setprio(1);
#pragma unroll
  for (int c = 0; c < 4; ++c) {
    const char* base = bV + (c * 16 + cl) * 128;
    bf16x8 v0 = *(const bf16x8*)(base + ((gp * 16) ^ swz));
    bf16x8 v1 = *(const bf16x8*)(base + ((64 + gp * 16) ^ swz));
    if (act0) {
      o0[c] = MFMA16(pa00, v0, o0[c]);
      o0[c] = MFMA16(pa01, v1, o0[c]);
    }
    o1[c] = MFMA16(pa10, v0, o1[c]);
    o1[c] = MFMA16(pa11, v1, o1[c]);
  }
  __builtin_amdgcn_s_setprio(0);
  asm volatile("" ::: "memory");            // pa reads done before next pass rewrites P
}

// ---- attention v4: paired q-tiles (j, 15-j) per block, uniform work, XCD-local ----
__global__ __launch_bounds__(256) void k_attn4(const bf16_t* __restrict__ qkv,
                                               const bf16_t* __restrict__ kh,
                                               const bf16_t* __restrict__ vT,
                                               bf16_t* __restrict__ out) {
  __shared__ alignas(16) char sK[2][8192];     // [64 kv][128B d], XOR-swizzled
  __shared__ alignas(16) char sV[2][8192];     // [64 d][128B kv], XOR-swizzled
  __shared__ alignas(16) char sP[4][2][2048];  // per wave: two 16q x 128B P buffers

  int n = blockIdx.x;
  int bh = ((n & 7) << 3) | ((n >> 3) & 7);    // same head -> same XCD (n%8 const)
  int j = n >> 6;                              // 0..7
  int b = bh >> 4, h = bh & 15;
  int tid = threadIdx.x, wid = tid >> 6, lane = tid & 63;
  int cl = lane & 15, gp = lane >> 4;

  int qb0 = j * 128;                           // lo q-tile
  int qb1 = (15 - j) * 128;                    // hi q-tile
  int qwL0 = qb0 + wid * 16, qwL1 = qb0 + 64 + wid * 16;
  int qwH0 = qb1 + wid * 16, qwH1 = qb1 + 64 + wid * 16;

  // Q fragments (B-operand): col=cl(q), k(d)=gp*8+e. kh carries the 1/8 scale.
  bf16x8 qfL[2][2], qfH[2][2];
  {
    const bf16_t* p;
    p = qkv + (size_t)(b * 2048 + qwL0 + cl) * 3072 + h * 64 + gp * 8;
    qfL[0][0] = *(const bf16x8*)p; qfL[0][1] = *(const bf16x8*)(p + 32);
    p = qkv + (size_t)(b * 2048 + qwL1 + cl) * 3072 + h * 64 + gp * 8;
    qfL[1][0] = *(const bf16x8*)p; qfL[1][1] = *(const bf16x8*)(p + 32);
    p = qkv + (size_t)(b * 2048 + qwH0 + cl) * 3072 + h * 64 + gp * 8;
    qfH[0][0] = *(const bf16x8*)p; qfH[0][1] = *(const bf16x8*)(p + 32);
    p = qkv + (size_t)(b * 2048 + qwH1 + cl) * 3072 + h * 64 + gp * 8;
    qfH[1][0] = *(const bf16x8*)p; qfH[1][1] = *(const bf16x8*)(p + 32);
  }

  int srow = tid >> 3;
  int swzcb = ((tid & 7) * 16) ^ ((srow & 7) << 4);
  const bf16_t* gK = kh + ((size_t)bh * 2048 + srow) * 64 + (swzcb >> 1);
  const bf16_t* gV = vT + ((size_t)(bh * 64) + srow) * 2048 + (swzcb >> 1);

  f32x4 oL0[4], oL1[4], oH0[4], oH1[4];
#pragma unroll
  for (int c = 0; c < 4; ++c) { oL0[c] = zero4(); oL1[c] = zero4(); oH0[c] = zero4(); oH1[c] = zero4(); }
  float mrunL[2] = {-1e30f, -1e30f}, lsumL[2] = {0.f, 0.f};
  float mrunH[2] = {-1e30f, -1e30f}, lsumH[2] = {0.f, 0.f};

  int swz = (cl & 7) << 4;
  int nt = 32 - 2 * j;                         // KV64 tiles for the hi q-tile

  {
    char* lK = sK[0] + wid * 1024;
    char* lV = sV[0] + wid * 1024;
    GLOAD_LDS16(gK, lK);
    GLOAD_LDS16(gK + 32 * 64, lK + 4096);
    GLOAD_LDS16(gV, lV);
    GLOAD_LDS16(gV + (size_t)32 * 2048, lV + 4096);
  }
  asm volatile("s_waitcnt vmcnt(0)");
  __syncthreads();

  for (int t = 0; t < nt; ++t) {
    int cur = t & 1;
    int kv0 = t * 64;
    if (t + 1 < nt) {
      int kv1 = kv0 + 64;
      char* lK = sK[cur ^ 1] + wid * 1024;
      char* lV = sV[cur ^ 1] + wid * 1024;
      GLOAD_LDS16(gK + (size_t)kv1 * 64, lK);
      GLOAD_LDS16(gK + (size_t)(kv1 + 32) * 64, lK + 4096);
      GLOAD_LDS16(gV + kv1, lV);
      GLOAD_LDS16(gV + kv1 + (size_t)32 * 2048, lV + 4096);
    }
    const char* bK = sK[cur];
    const char* bV = sV[cur];

    if (kv0 <= qwL1 + 15)
      attn_pass(bK, bV, sP[wid][0], sP[wid][1], qfL, oL0, oL1, mrunL, lsumL,
                kv0, qwL0, qwL1, swz, cl, gp, kv0 <= qwL0 + 15);
    attn_pass(bK, bV, sP[wid][0], sP[wid][1], qfH, oH0, oH1, mrunH, lsumH,
              kv0, qwH0, qwH1, swz, cl, gp, kv0 <= qwH0 + 15);

    asm volatile("s_waitcnt vmcnt(0)");
    __syncthreads();
  }

  // epilogue: redistribute lsum (q=cl domain -> q=gp*4+e domain) and store
#pragma unroll
  for (int e = 0; e < 4; ++e) {
    float iL0 = 1.0f / __shfl(lsumL[0], gp * 4 + e);
    float iL1 = 1.0f / __shfl(lsumL[1], gp * 4 + e);
    float iH0 = 1.0f / __shfl(lsumH[0], gp * 4 + e);
    float iH1 = 1.0f / __shfl(lsumH[1], gp * 4 + e);
    int rL0 = qwL0 + gp * 4 + e, rL1 = qwL1 + gp * 4 + e;
    int rH0 = qwH0 + gp * 4 + e, rH1 = qwH1 + gp * 4 + e;
#pragma unroll
    for (int c = 0; c < 4; ++c) {
      int col = h * 64 + c * 16 + cl;
      out[(size_t)(b * 2048 + rL0) * 1024 + col] = (bf16_t)(oL0[c][e] * iL0);
      out[(size_t)(b * 2048 + rL1) * 1024 + col] = (bf16_t)(oL1[c][e] * iL1);
      out[(size_t)(b * 2048 + rH0) * 1024 + col] = (bf16_t)(oH0[c][e] * iH0);
      out[(size_t)(b * 2048 + rH1) * 1024 + col] = (bf16_t)(oH1[c][e] * iH1);
    }
  }
}

// ---------------------------------------------------------------------------
extern "C" void kernel_launch(void* const* d_in, const int* in_sizes, int n_in,
                              void* d_out, int out_size, void* d_ws, size_t ws_size,
                              hipStream_t stream) {
  const float* x      = (const float*)d_in[0];
  const float* w_qkv  = (const float*)d_in[1];
  const float* w_proj = (const float*)d_in[2];
  const float* b_proj = (const float*)d_in[3];
  float* outp = (float*)d_out;

  char* ws = (char*)d_ws;
  bf16_t* xb     = (bf16_t*)(ws);                                      // 16 MiB
  bf16_t* wqkvT  = (bf16_t*)(ws + 16777216);                           // 6 MiB
  bf16_t* wprojT = (bf16_t*)(ws + 16777216 + 6291456);                 // 2 MiB
  bf16_t* qkv    = (bf16_t*)(ws + 16777216 + 6291456 + 2097152);       // 48 MiB
  bf16_t* vT     = (bf16_t*)(ws + 16777216 + 6291456 + 2097152 + 50331648);
  bf16_t* aout   = (bf16_t*)(ws + 16777216 + 6291456 + 2097152 + 50331648 + 16777216);
  bf16_t* kh     = xb;   // reuse xb region after GEMM1 consumed it

  k_cast<<<dim3(8192 * 1024 / (256 * 8)), 256, 0, stream>>>(x, xb);
  k_tcast<<<dim3(3072 / 64, 1024 / 64), 256, 0, stream>>>(w_qkv, wqkvT, 1024, 3072);
  k_tcast<<<dim3(1024 / 64, 1024 / 64), 256, 0, stream>>>(w_proj, wprojT, 1024, 1024);
  k_gemm_bt<true><<<dim3(3072 / 128, 8192 / 128), 256, 0, stream>>>(
      xb, wqkvT, (void*)qkv, nullptr, 8192, 3072, 1024);
  k_kprep<<<dim3(32, 64), 256, 0, stream>>>(qkv, kh);
  k_vtrans<<<dim3(32, 64), 256, 0, stream>>>(qkv, vT);
  k_attn4<<<dim3(512), 256, 0, stream>>>(qkv, kh, vT, aout);
  k_gemm_bt<false><<<dim3(1024 / 128, 8192 / 128), 256, 0, stream>>>(
      aout, wprojT, (void*)outp, b_proj, 8192, 1024, 1024);
}

// Round 5
// 286.670 us; speedup vs baseline: 1.8652x; 1.2447x over previous
//
#include <hip/hip_runtime.h>
#include <hip/hip_bf16.h>
#include <stdint.h>
#include <stddef.h>

typedef __bf16 bf16_t;
typedef __bf16 bf16x4 __attribute__((ext_vector_type(4)));
typedef __bf16 bf16x8 __attribute__((ext_vector_type(8)));
typedef float  f32x4  __attribute__((ext_vector_type(4)));

static __device__ __forceinline__ f32x4 zero4() { return (f32x4){0.f, 0.f, 0.f, 0.f}; }

#define MFMA16(a, b, c) __builtin_amdgcn_mfma_f32_16x16x32_bf16((a), (b), (c), 0, 0, 0)

#define GLOAD_LDS16(gptr, lptr)                                                        \
  __builtin_amdgcn_global_load_lds((const __attribute__((address_space(1))) void*)(gptr), \
                                   (__attribute__((address_space(3))) void*)(lptr), 16, 0, 0)

// ---------------- cast x fp32 -> bf16, 8 elems/thread ----------------
__global__ __launch_bounds__(256) void k_cast(const float* __restrict__ in,
                                              bf16_t* __restrict__ out) {
  size_t i = (size_t)blockIdx.x * 256 + threadIdx.x;
  const float4* p = (const float4*)in;
  float4 a = p[i * 2 + 0];
  float4 b = p[i * 2 + 1];
  bf16x8 v;
  v[0] = (bf16_t)a.x; v[1] = (bf16_t)a.y; v[2] = (bf16_t)a.z; v[3] = (bf16_t)a.w;
  v[4] = (bf16_t)b.x; v[5] = (bf16_t)b.y; v[6] = (bf16_t)b.z; v[7] = (bf16_t)b.w;
  *(bf16x8*)(out + i * 8) = v;
}

// ------------- transpose-cast: in fp32 [R][C] -> out bf16 [C][R] -------------
__global__ __launch_bounds__(256) void k_tcast(const float* __restrict__ in,
                                               bf16_t* __restrict__ out,
                                               int R, int C) {
  __shared__ bf16_t tile[64][72];
  int c0 = blockIdx.x * 64, r0 = blockIdx.y * 64;
  int t = threadIdx.x;
  int r = t >> 2, cc = (t & 3) * 16;
  const float* src = in + (size_t)(r0 + r) * C + c0 + cc;
#pragma unroll
  for (int q = 0; q < 4; ++q) {
    float4 v = *(const float4*)(src + q * 4);
    tile[r][cc + q * 4 + 0] = (bf16_t)v.x;
    tile[r][cc + q * 4 + 1] = (bf16_t)v.y;
    tile[r][cc + q * 4 + 2] = (bf16_t)v.z;
    tile[r][cc + q * 4 + 3] = (bf16_t)v.w;
  }
  __syncthreads();
  int c = t >> 2, rr = (t & 3) * 16;
  bf16x8 o0, o1;
#pragma unroll
  for (int j = 0; j < 8; ++j) { o0[j] = tile[rr + j][c]; o1[j] = tile[rr + 8 + j][c]; }
  bf16_t* dst = out + (size_t)(c0 + c) * R + r0 + rr;
  *(bf16x8*)dst = o0;
  *(bf16x8*)(dst + 8) = o1;
}

// ------- V transpose: qkv bf16 [8192][3072] -> vT bf16 [(bh*64+d)][2048] -------
__global__ __launch_bounds__(256) void k_vtrans(const bf16_t* __restrict__ qkv,
                                                bf16_t* __restrict__ vT) {
  __shared__ bf16_t tile[64][72];
  int t0 = blockIdx.x * 64, bh = blockIdx.y;
  int b = bh >> 4, h = bh & 15;
  int t = threadIdx.x;
  int tr = t >> 2, cc = (t & 3) * 16;
  const bf16_t* src = qkv + (size_t)(b * 2048 + t0 + tr) * 3072 + 2048 + h * 64 + cc;
  bf16x8 a0 = *(const bf16x8*)src;
  bf16x8 a1 = *(const bf16x8*)(src + 8);
#pragma unroll
  for (int j = 0; j < 8; ++j) { tile[tr][cc + j] = a0[j]; tile[tr][cc + 8 + j] = a1[j]; }
  __syncthreads();
  int d = t >> 2, tt = (t & 3) * 16;
  bf16x8 o0, o1;
#pragma unroll
  for (int j = 0; j < 8; ++j) { o0[j] = tile[tt + j][d]; o1[j] = tile[tt + 8 + j][d]; }
  bf16_t* dst = vT + (size_t)(bh * 64 + d) * 2048 + t0 + tt;
  *(bf16x8*)dst = o0;
  *(bf16x8*)(dst + 8) = o1;
}

// -- K prep: qkv -> kh bf16 [bh][2048][64], scaled by log2(e)/8 (exp2 domain) --
__global__ __launch_bounds__(256) void k_kprep(const bf16_t* __restrict__ qkv,
                                               bf16_t* __restrict__ kh) {
  int t0 = blockIdx.x * 64, bh = blockIdx.y;
  int b = bh >> 4, h = bh & 15;
  int t = threadIdx.x;
  int r = t >> 2, c = (t & 3) * 16;
  const bf16_t* src = qkv + (size_t)(b * 2048 + t0 + r) * 3072 + 1024 + h * 64 + c;
  bf16x8 a0 = *(const bf16x8*)src;
  bf16x8 a1 = *(const bf16x8*)(src + 8);
#pragma unroll
  for (int j = 0; j < 8; ++j) {
    a0[j] = (bf16_t)(0.18033688011f * (float)a0[j]);
    a1[j] = (bf16_t)(0.18033688011f * (float)a1[j]);
  }
  bf16_t* dst = kh + ((size_t)bh * 2048 + t0 + r) * 64 + c;
  *(bf16x8*)dst = a0;
  *(bf16x8*)(dst + 8) = a1;
}

// ---------------- GEMM: C[M][N] = A[M][K] * BT[N][K]^T (+bias) ----------------
template <bool BF16OUT>
__global__ __launch_bounds__(256) void k_gemm_bt(const bf16_t* __restrict__ A,
                                                 const bf16_t* __restrict__ BT,
                                                 void* __restrict__ Cout,
                                                 const float* __restrict__ bias,
                                                 int M, int N, int K) {
  __shared__ bf16_t sA[128 * 32];
  __shared__ bf16_t sB[128 * 32];
  int tid = threadIdx.x;
  int wid = tid >> 6, lane = tid & 63;
  int cl = lane & 15, gp = lane >> 4;
  int nwg = gridDim.x * gridDim.y;
  int flat = blockIdx.y * gridDim.x + blockIdx.x;
  int cpx = nwg >> 3;
  int swzid = (flat & 7) * cpx + (flat >> 3);
  int brow = (swzid / gridDim.x) * 128, bcol = (swzid % gridDim.x) * 128;
  int wr = wid >> 1, wc = wid & 1;
  f32x4 acc[4][4];
#pragma unroll
  for (int i = 0; i < 4; ++i)
#pragma unroll
    for (int j = 0; j < 4; ++j) acc[i][j] = zero4();

  int srow = tid >> 2;
  int sk = (tid & 3) * 8;
  const bf16_t* gA = A + (size_t)(brow + srow) * K + sk;
  const bf16_t* gB = BT + (size_t)(bcol + srow) * K + sk;
  char* lA = (char*)sA + wid * 1024;
  char* lB = (char*)sB + wid * 1024;

  for (int k0 = 0; k0 < K; k0 += 32) {
    __syncthreads();
    GLOAD_LDS16(gA + k0, lA);
    GLOAD_LDS16(gA + (size_t)64 * K + k0, lA + 4096);
    GLOAD_LDS16(gB + k0, lB);
    GLOAD_LDS16(gB + (size_t)64 * K + k0, lB + 4096);
    __syncthreads();
    bf16x8 af[4], bfr[4];
#pragma unroll
    for (int i = 0; i < 4; ++i)
      af[i] = *(const bf16x8*)&sA[(wr * 64 + i * 16 + cl) * 32 + gp * 8];
#pragma unroll
    for (int j = 0; j < 4; ++j)
      bfr[j] = *(const bf16x8*)&sB[(wc * 64 + j * 16 + cl) * 32 + gp * 8];
#pragma unroll
    for (int i = 0; i < 4; ++i)
#pragma unroll
      for (int j = 0; j < 4; ++j)
        acc[i][j] = MFMA16(af[i], bfr[j], acc[i][j]);
  }

#pragma unroll
  for (int i = 0; i < 4; ++i) {
    int row0 = brow + wr * 64 + i * 16 + gp * 4;
#pragma unroll
    for (int j = 0; j < 4; ++j) {
      int col = bcol + wc * 64 + j * 16 + cl;
#pragma unroll
      for (int e = 0; e < 4; ++e) {
        size_t idx = (size_t)(row0 + e) * N + col;
        if (BF16OUT)
          ((bf16_t*)Cout)[idx] = (bf16_t)acc[i][j][e];
        else
          ((float*)Cout)[idx] = acc[i][j][e] + bias[col];
      }
    }
  }
}

// ---------------- attention v5 helpers (exp2 domain) ----------------
static __device__ __forceinline__ void softmax16(f32x4 (&s)[4], f32x4 (&o)[4],
                                                 float& mrun, float& lsum, char* Pw,
                                                 int kv0, int qw, int swz, int cl, int gp) {
  if (kv0 + 63 > qw) {                        // only the diagonal tile masks
    int thr = qw + cl - kv0 - gp * 4;         // elem (jj,e) masked iff jj*16+e > thr
#pragma unroll
    for (int jj = 0; jj < 4; ++jj)
#pragma unroll
      for (int e = 0; e < 4; ++e)
        if (jj * 16 + e > thr) s[jj][e] = -1e30f;
  }
  float pm01 = fmaxf(fmaxf(fmaxf(s[0][0], s[0][1]), fmaxf(s[0][2], s[0][3])),
                     fmaxf(fmaxf(s[1][0], s[1][1]), fmaxf(s[1][2], s[1][3])));
  float pm23 = fmaxf(fmaxf(fmaxf(s[2][0], s[2][1]), fmaxf(s[2][2], s[2][3])),
                     fmaxf(fmaxf(s[3][0], s[3][1]), fmaxf(s[3][2], s[3][3])));
  float pm = fmaxf(pm01, pm23);
  pm = fmaxf(pm, __shfl_xor(pm, 16));
  pm = fmaxf(pm, __shfl_xor(pm, 32));
  float mnew = mrun;
  if (!__all(pm <= mnew + 11.5f)) {           // defer-max (T13), log2 domain
    float mold = mnew;
    mnew = fmaxf(mold, pm);
    float aa = exp2f(mold - mnew);
    mrun = mnew;
    lsum *= aa;
#pragma unroll
    for (int e = 0; e < 4; ++e) {
      float ae = __shfl(aa, gp * 4 + e);
#pragma unroll
      for (int c = 0; c < 4; ++c) o[c][e] *= ae;
    }
  }
  float rsj[4];
#pragma unroll
  for (int jj = 0; jj < 4; ++jj) {
    float p0 = exp2f(s[jj][0] - mnew);
    float p1 = exp2f(s[jj][1] - mnew);
    float p2 = exp2f(s[jj][2] - mnew);
    float p3 = exp2f(s[jj][3] - mnew);
    rsj[jj] = (p0 + p1) + (p2 + p3);
    bf16x4 pw;
    pw[0] = (bf16_t)p0; pw[1] = (bf16_t)p1; pw[2] = (bf16_t)p2; pw[3] = (bf16_t)p3;
    *(bf16x4*)(Pw + cl * 128 + ((jj * 32 + gp * 8) ^ swz)) = pw;
  }
  float rs = (rsj[0] + rsj[1]) + (rsj[2] + rsj[3]);
  rs += __shfl_xor(rs, 16);
  rs += __shfl_xor(rs, 32);
  lsum += rs;
}

// one 16-q-row pass over the current KV64 tile
static __device__ __forceinline__ void pass16(const char* __restrict__ bK,
                                              const char* __restrict__ bV,
                                              char* __restrict__ Pw,
                                              const bf16x8& qa, const bf16x8& qb,
                                              f32x4 (&o)[4], float& mrun, float& lsum,
                                              int kv0, int qw, int swz, int cl, int gp) {
  f32x4 s[4];
#pragma unroll
  for (int jj = 0; jj < 4; ++jj) {
    const char* base = bK + (jj * 16 + cl) * 128;
    bf16x8 k0 = *(const bf16x8*)(base + ((gp * 16) ^ swz));
    bf16x8 k1 = *(const bf16x8*)(base + ((64 + gp * 16) ^ swz));
    f32x4 a = zero4();
    a = MFMA16(k0, qa, a);
    a = MFMA16(k1, qb, a);
    s[jj] = a;
  }
  softmax16(s, o, mrun, lsum, Pw, kv0, qw, swz, cl, gp);

  asm volatile("" ::: "memory");              // P writes before P reads (same wave)
  bf16x8 pa0 = *(const bf16x8*)(Pw + cl * 128 + ((gp * 16) ^ swz));
  bf16x8 pa1 = *(const bf16x8*)(Pw + cl * 128 + ((64 + gp * 16) ^ swz));

  __builtin_amdgcn_s_setprio(1);
#pragma unroll
  for (int c = 0; c < 4; ++c) {
    const char* base = bV + (c * 16 + cl) * 128;
    bf16x8 v0 = *(const bf16x8*)(base + ((gp * 16) ^ swz));
    bf16x8 v1 = *(const bf16x8*)(base + ((64 + gp * 16) ^ swz));
    o[c] = MFMA16(pa0, v0, o[c]);
    o[c] = MFMA16(pa1, v1, o[c]);
  }
  __builtin_amdgcn_s_setprio(0);
  asm volatile("" ::: "memory");              // pa/v reads done before P rewrite
}

// ---- attention v5: QBLK=64, paired q-tiles (jL, 31-jL), 4 blocks/CU ----
__global__ __launch_bounds__(256, 4) void k_attn5(const bf16_t* __restrict__ qkv,
                                                  const bf16_t* __restrict__ kh,
                                                  const bf16_t* __restrict__ vT,
                                                  bf16_t* __restrict__ out) {
  __shared__ alignas(16) char sK[2][8192];     // [64 kv][128B d], XOR-swizzled
  __shared__ alignas(16) char sV[2][8192];     // [64 d][128B kv], XOR-swizzled
  __shared__ alignas(16) char sP[4][2048];     // per wave: 16q x 128B P buffer

  int n = blockIdx.x;
  int bh = ((n & 7) << 3) | ((n >> 3) & 7);    // same head group -> same XCD
  int pr = n >> 6;                             // 0..15
  int jL = pr, jH = 31 - pr;                   // paired q-tiles: uniform work
  int b = bh >> 4, h = bh & 15;
  int tid = threadIdx.x, wid = tid >> 6, lane = tid & 63;
  int cl = lane & 15, gp = lane >> 4;

  int qwL = jL * 64 + wid * 16;
  int qwH = jH * 64 + wid * 16;

  // Q fragments (B-operand): col=cl(q), k(d)=gp*8+e. kh carries scale.
  bf16x8 qL0, qL1, qH0, qH1;
  {
    const bf16_t* p = qkv + (size_t)(b * 2048 + qwL + cl) * 3072 + h * 64 + gp * 8;
    qL0 = *(const bf16x8*)p; qL1 = *(const bf16x8*)(p + 32);
    p = qkv + (size_t)(b * 2048 + qwH + cl) * 3072 + h * 64 + gp * 8;
    qH0 = *(const bf16x8*)p; qH1 = *(const bf16x8*)(p + 32);
  }

  int srow = tid >> 3;
  int swzcb = ((tid & 7) * 16) ^ ((srow & 7) << 4);
  const bf16_t* gK = kh + ((size_t)bh * 2048 + srow) * 64 + (swzcb >> 1);
  const bf16_t* gV = vT + ((size_t)(bh * 64) + srow) * 2048 + (swzcb >> 1);

  f32x4 oL[4], oH[4];
#pragma unroll
  for (int c = 0; c < 4; ++c) { oL[c] = zero4(); oH[c] = zero4(); }
  float mrunL = -1e30f, lsumL = 0.f, mrunH = -1e30f, lsumH = 0.f;

  int swz = (cl & 7) << 4;
  int nt = jH + 1;                             // KV64 tiles (H's causal extent)
  char* Pw = sP[wid];

  {
    char* lK = sK[0] + wid * 1024;
    char* lV = sV[0] + wid * 1024;
    GLOAD_LDS16(gK, lK);
    GLOAD_LDS16(gK + 32 * 64, lK + 4096);
    GLOAD_LDS16(gV, lV);
    GLOAD_LDS16(gV + (size_t)32 * 2048, lV + 4096);
  }
  asm volatile("s_waitcnt vmcnt(0)");
  __syncthreads();

  for (int t = 0; t < nt; ++t) {
    int cur = t & 1;
    int kv0 = t * 64;
    if (t + 1 < nt) {
      int kv1 = kv0 + 64;
      char* lK = sK[cur ^ 1] + wid * 1024;
      char* lV = sV[cur ^ 1] + wid * 1024;
      GLOAD_LDS16(gK + (size_t)kv1 * 64, lK);
      GLOAD_LDS16(gK + (size_t)(kv1 + 32) * 64, lK + 4096);
      GLOAD_LDS16(gV + kv1, lV);
      GLOAD_LDS16(gV + kv1 + (size_t)32 * 2048, lV + 4096);
    }
    const char* bK = sK[cur];
    const char* bV = sV[cur];

    if (t <= jL)
      pass16(bK, bV, Pw, qL0, qL1, oL, mrunL, lsumL, kv0, qwL, swz, cl, gp);
    pass16(bK, bV, Pw, qH0, qH1, oH, mrunH, lsumH, kv0, qwH, swz, cl, gp);

    asm volatile("s_waitcnt vmcnt(0)");
    __syncthreads();
  }

  // epilogue: redistribute lsum (q=cl domain -> q=gp*4+e domain) and store
#pragma unroll
  for (int e = 0; e < 4; ++e) {
    float iL = 1.0f / __shfl(lsumL, gp * 4 + e);
    float iH = 1.0f / __shfl(lsumH, gp * 4 + e);
    int rL = qwL + gp * 4 + e;
    int rH = qwH + gp * 4 + e;
#pragma unroll
    for (int c = 0; c < 4; ++c) {
      int col = h * 64 + c * 16 + cl;
      out[(size_t)(b * 2048 + rL) * 1024 + col] = (bf16_t)(oL[c][e] * iL);
      out[(size_t)(b * 2048 + rH) * 1024 + col] = (bf16_t)(oH[c][e] * iH);
    }
  }
}

// ---------------------------------------------------------------------------
extern "C" void kernel_launch(void* const* d_in, const int* in_sizes, int n_in,
                              void* d_out, int out_size, void* d_ws, size_t ws_size,
                              hipStream_t stream) {
  const float* x      = (const float*)d_in[0];
  const float* w_qkv  = (const float*)d_in[1];
  const float* w_proj = (const float*)d_in[2];
  const float* b_proj = (const float*)d_in[3];
  float* outp = (float*)d_out;

  char* ws = (char*)d_ws;
  bf16_t* xb     = (bf16_t*)(ws);                                      // 16 MiB
  bf16_t* wqkvT  = (bf16_t*)(ws + 16777216);                           // 6 MiB
  bf16_t* wprojT = (bf16_t*)(ws + 16777216 + 6291456);                 // 2 MiB
  bf16_t* qkv    = (bf16_t*)(ws + 16777216 + 6291456 + 2097152);       // 48 MiB
  bf16_t* vT     = (bf16_t*)(ws + 16777216 + 6291456 + 2097152 + 50331648);
  bf16_t* aout   = (bf16_t*)(ws + 16777216 + 6291456 + 2097152 + 50331648 + 16777216);
  bf16_t* kh     = xb;   // reuse xb region after GEMM1 consumed it

  k_cast<<<dim3(8192 * 1024 / (256 * 8)), 256, 0, stream>>>(x, xb);
  k_tcast<<<dim3(3072 / 64, 1024 / 64), 256, 0, stream>>>(w_qkv, wqkvT, 1024, 3072);
  k_tcast<<<dim3(1024 / 64, 1024 / 64), 256, 0, stream>>>(w_proj, wprojT, 1024, 1024);
  k_gemm_bt<true><<<dim3(3072 / 128, 8192 / 128), 256, 0, stream>>>(
      xb, wqkvT, (void*)qkv, nullptr, 8192, 3072, 1024);
  k_kprep<<<dim3(32, 64), 256, 0, stream>>>(qkv, kh);
  k_vtrans<<<dim3(32, 64), 256, 0, stream>>>(qkv, vT);
  k_attn5<<<dim3(1024), 256, 0, stream>>>(qkv, kh, vT, aout);
  k_gemm_bt<false><<<dim3(1024 / 128, 8192 / 128), 256, 0, stream>>>(
      aout, wprojT, (void*)outp, b_proj, 8192, 1024, 1024);
}

// Round 6
// 277.356 us; speedup vs baseline: 1.9278x; 1.0336x over previous
//
#include <hip/hip_runtime.h>
#include <hip/hip_bf16.h>
#include <stdint.h>
#include <stddef.h>

typedef __bf16 bf16_t;
typedef __bf16 bf16x4 __attribute__((ext_vector_type(4)));
typedef __bf16 bf16x8 __attribute__((ext_vector_type(8)));
typedef float  f32x4  __attribute__((ext_vector_type(4)));

static __device__ __forceinline__ f32x4 zero4() { return (f32x4){0.f, 0.f, 0.f, 0.f}; }

#define MFMA16(a, b, c) __builtin_amdgcn_mfma_f32_16x16x32_bf16((a), (b), (c), 0, 0, 0)

#define GLOAD_LDS16(gptr, lptr)                                                        \
  __builtin_amdgcn_global_load_lds((const __attribute__((address_space(1))) void*)(gptr), \
                                   (__attribute__((address_space(3))) void*)(lptr), 16, 0, 0)

// ---------------- cast x fp32 -> bf16, 8 elems/thread ----------------
__global__ __launch_bounds__(256) void k_cast(const float* __restrict__ in,
                                              bf16_t* __restrict__ out) {
  size_t i = (size_t)blockIdx.x * 256 + threadIdx.x;
  const float4* p = (const float4*)in;
  float4 a = p[i * 2 + 0];
  float4 b = p[i * 2 + 1];
  bf16x8 v;
  v[0] = (bf16_t)a.x; v[1] = (bf16_t)a.y; v[2] = (bf16_t)a.z; v[3] = (bf16_t)a.w;
  v[4] = (bf16_t)b.x; v[5] = (bf16_t)b.y; v[6] = (bf16_t)b.z; v[7] = (bf16_t)b.w;
  *(bf16x8*)(out + i * 8) = v;
}

// ------------- transpose-cast: in fp32 [R][C] -> out bf16 [C][R] -------------
__global__ __launch_bounds__(256) void k_tcast(const float* __restrict__ in,
                                               bf16_t* __restrict__ out,
                                               int R, int C) {
  __shared__ bf16_t tile[64][72];
  int c0 = blockIdx.x * 64, r0 = blockIdx.y * 64;
  int t = threadIdx.x;
  int r = t >> 2, cc = (t & 3) * 16;
  const float* src = in + (size_t)(r0 + r) * C + c0 + cc;
#pragma unroll
  for (int q = 0; q < 4; ++q) {
    float4 v = *(const float4*)(src + q * 4);
    tile[r][cc + q * 4 + 0] = (bf16_t)v.x;
    tile[r][cc + q * 4 + 1] = (bf16_t)v.y;
    tile[r][cc + q * 4 + 2] = (bf16_t)v.z;
    tile[r][cc + q * 4 + 3] = (bf16_t)v.w;
  }
  __syncthreads();
  int c = t >> 2, rr = (t & 3) * 16;
  bf16x8 o0, o1;
#pragma unroll
  for (int j = 0; j < 8; ++j) { o0[j] = tile[rr + j][c]; o1[j] = tile[rr + 8 + j][c]; }
  bf16_t* dst = out + (size_t)(c0 + c) * R + r0 + rr;
  *(bf16x8*)dst = o0;
  *(bf16x8*)(dst + 8) = o1;
}

// ---- fused QKV GEMM: qkv = xb @ wqkvT^T, epilogue scatters to qh/kh/vT ----
// qh[bh][2048][64]; kh[bh][2048][64] scaled by log2(e)/8; vT[bh*64+d][2048].
__global__ __launch_bounds__(256) void k_gemm_qkv(const bf16_t* __restrict__ A,
                                                  const bf16_t* __restrict__ BT,
                                                  bf16_t* __restrict__ qh,
                                                  bf16_t* __restrict__ kh,
                                                  bf16_t* __restrict__ vT) {
  constexpr int K = 1024;
  __shared__ bf16_t sA[128 * 32];
  __shared__ bf16_t sB[128 * 32];
  __shared__ bf16_t vtile[4][64][72];          // per-wave V transpose staging
  int tid = threadIdx.x;
  int wid = tid >> 6, lane = tid & 63;
  int cl = lane & 15, gp = lane >> 4;
  int nwg = gridDim.x * gridDim.y;
  int flat = blockIdx.y * gridDim.x + blockIdx.x;
  int cpx = nwg >> 3;
  int swzid = (flat & 7) * cpx + (flat >> 3);
  int brow = (swzid / gridDim.x) * 128, bcol = (swzid % gridDim.x) * 128;
  int wr = wid >> 1, wc = wid & 1;
  f32x4 acc[4][4];
#pragma unroll
  for (int i = 0; i < 4; ++i)
#pragma unroll
    for (int j = 0; j < 4; ++j) acc[i][j] = zero4();

  int srow = tid >> 2;
  int sk = (tid & 3) * 8;
  const bf16_t* gA = A + (size_t)(brow + srow) * K + sk;
  const bf16_t* gB = BT + (size_t)(bcol + srow) * K + sk;
  char* lA = (char*)sA + wid * 1024;
  char* lB = (char*)sB + wid * 1024;

  for (int k0 = 0; k0 < K; k0 += 32) {
    __syncthreads();
    GLOAD_LDS16(gA + k0, lA);
    GLOAD_LDS16(gA + (size_t)64 * K + k0, lA + 4096);
    GLOAD_LDS16(gB + k0, lB);
    GLOAD_LDS16(gB + (size_t)64 * K + k0, lB + 4096);
    __syncthreads();
    bf16x8 af[4], bfr[4];
#pragma unroll
    for (int i = 0; i < 4; ++i)
      af[i] = *(const bf16x8*)&sA[(wr * 64 + i * 16 + cl) * 32 + gp * 8];
#pragma unroll
    for (int j = 0; j < 4; ++j)
      bfr[j] = *(const bf16x8*)&sB[(wc * 64 + j * 16 + cl) * 32 + gp * 8];
#pragma unroll
    for (int i = 0; i < 4; ++i)
#pragma unroll
      for (int j = 0; j < 4; ++j)
        acc[i][j] = MFMA16(af[i], bfr[j], acc[i][j]);
  }

  // epilogue: this wave's 64-col span = exactly one head of one region
  int b_ = brow >> 11;                         // batch (2048 rows each)
  int t0 = (brow & 2047) + wr * 64;            // token offset of this wave
  int colbase = bcol + wc * 64;
  int region = colbase >> 10;                  // 0=Q 1=K 2=V
  int h_ = (colbase & 1023) >> 6;
  size_t bh_ = (size_t)(b_ * 16 + h_);

  if (region < 2) {
    bf16_t* dst = (region == 0 ? qh : kh) + (bh_ * 2048 + t0) * 64;
    float sc = (region == 0) ? 1.0f : 0.18033688011f;   // log2(e)/8 for K
#pragma unroll
    for (int i = 0; i < 4; ++i)
#pragma unroll
      for (int j = 0; j < 4; ++j)
#pragma unroll
        for (int e = 0; e < 4; ++e)
          dst[(size_t)(i * 16 + gp * 4 + e) * 64 + j * 16 + cl] =
              (bf16_t)(acc[i][j][e] * sc);
  } else {
    bf16_t (*vt)[72] = vtile[wid];             // wave-private -> no barrier
#pragma unroll
    for (int i = 0; i < 4; ++i)
#pragma unroll
      for (int j = 0; j < 4; ++j)
#pragma unroll
        for (int e = 0; e < 4; ++e)
          vt[j * 16 + cl][i * 16 + gp * 4 + e] = (bf16_t)acc[i][j][e];
    int d = lane;
    const bf16_t* src = &vt[d][0];
    bf16_t* dst = vT + (bh_ * 64 + d) * 2048 + t0;
#pragma unroll
    for (int tt = 0; tt < 64; tt += 8)
      *(bf16x8*)(dst + tt) = *(const bf16x8*)(src + tt);
  }
}

// ---------------- GEMM: C[M][N] = A[M][K] * BT[N][K]^T + bias (fp32 out) ----------------
__global__ __launch_bounds__(256) void k_gemm_proj(const bf16_t* __restrict__ A,
                                                   const bf16_t* __restrict__ BT,
                                                   float* __restrict__ Cout,
                                                   const float* __restrict__ bias,
                                                   int M, int N, int K) {
  __shared__ bf16_t sA[128 * 32];
  __shared__ bf16_t sB[128 * 32];
  int tid = threadIdx.x;
  int wid = tid >> 6, lane = tid & 63;
  int cl = lane & 15, gp = lane >> 4;
  int nwg = gridDim.x * gridDim.y;
  int flat = blockIdx.y * gridDim.x + blockIdx.x;
  int cpx = nwg >> 3;
  int swzid = (flat & 7) * cpx + (flat >> 3);
  int brow = (swzid / gridDim.x) * 128, bcol = (swzid % gridDim.x) * 128;
  int wr = wid >> 1, wc = wid & 1;
  f32x4 acc[4][4];
#pragma unroll
  for (int i = 0; i < 4; ++i)
#pragma unroll
    for (int j = 0; j < 4; ++j) acc[i][j] = zero4();

  int srow = tid >> 2;
  int sk = (tid & 3) * 8;
  const bf16_t* gA = A + (size_t)(brow + srow) * K + sk;
  const bf16_t* gB = BT + (size_t)(bcol + srow) * K + sk;
  char* lA = (char*)sA + wid * 1024;
  char* lB = (char*)sB + wid * 1024;

  for (int k0 = 0; k0 < K; k0 += 32) {
    __syncthreads();
    GLOAD_LDS16(gA + k0, lA);
    GLOAD_LDS16(gA + (size_t)64 * K + k0, lA + 4096);
    GLOAD_LDS16(gB + k0, lB);
    GLOAD_LDS16(gB + (size_t)64 * K + k0, lB + 4096);
    __syncthreads();
    bf16x8 af[4], bfr[4];
#pragma unroll
    for (int i = 0; i < 4; ++i)
      af[i] = *(const bf16x8*)&sA[(wr * 64 + i * 16 + cl) * 32 + gp * 8];
#pragma unroll
    for (int j = 0; j < 4; ++j)
      bfr[j] = *(const bf16x8*)&sB[(wc * 64 + j * 16 + cl) * 32 + gp * 8];
#pragma unroll
    for (int i = 0; i < 4; ++i)
#pragma unroll
      for (int j = 0; j < 4; ++j)
        acc[i][j] = MFMA16(af[i], bfr[j], acc[i][j]);
  }

#pragma unroll
  for (int i = 0; i < 4; ++i) {
    int row0 = brow + wr * 64 + i * 16 + gp * 4;
#pragma unroll
    for (int j = 0; j < 4; ++j) {
      int col = bcol + wc * 64 + j * 16 + cl;
#pragma unroll
      for (int e = 0; e < 4; ++e)
        Cout[(size_t)(row0 + e) * N + col] = acc[i][j][e] + bias[col];
    }
  }
}

// ---------------- attention v6 (exp2 domain, lsum via ones-MFMA) ----------------
static __device__ __forceinline__ void pass16(const char* __restrict__ bK,
                                              const char* __restrict__ bV,
                                              char* __restrict__ Pw,
                                              const bf16x8& qa, const bf16x8& qb,
                                              const bf16x8& ones8,
                                              f32x4 (&o)[4], f32x4& ol, float& mrun,
                                              int kv0, int qw, int swz, int cl, int gp) {
  f32x4 s[4];
  __builtin_amdgcn_s_setprio(1);
#pragma unroll
  for (int jj = 0; jj < 4; ++jj) {
    const char* base = bK + (jj * 16 + cl) * 128;
    bf16x8 k0 = *(const bf16x8*)(base + ((gp * 16) ^ swz));
    bf16x8 k1 = *(const bf16x8*)(base + ((64 + gp * 16) ^ swz));
    f32x4 a = zero4();
    a = MFMA16(k0, qa, a);
    a = MFMA16(k1, qb, a);
    s[jj] = a;
  }
  __builtin_amdgcn_s_setprio(0);

  if (kv0 + 63 > qw) {                        // only the diagonal tile masks
    int thr = qw + cl - kv0 - gp * 4;         // elem (jj,e) masked iff jj*16+e > thr
#pragma unroll
    for (int jj = 0; jj < 4; ++jj)
#pragma unroll
      for (int e = 0; e < 4; ++e)
        if (jj * 16 + e > thr) s[jj][e] = -1e30f;
  }
  float pm01 = fmaxf(fmaxf(fmaxf(s[0][0], s[0][1]), fmaxf(s[0][2], s[0][3])),
                     fmaxf(fmaxf(s[1][0], s[1][1]), fmaxf(s[1][2], s[1][3])));
  float pm23 = fmaxf(fmaxf(fmaxf(s[2][0], s[2][1]), fmaxf(s[2][2], s[2][3])),
                     fmaxf(fmaxf(s[3][0], s[3][1]), fmaxf(s[3][2], s[3][3])));
  float pm = fmaxf(pm01, pm23);
  pm = fmaxf(pm, __shfl_xor(pm, 16));
  pm = fmaxf(pm, __shfl_xor(pm, 32));
  float mnew = mrun;
  if (!__all(pm <= mnew + 11.5f)) {           // defer-max (T13), log2 domain
    float mold = mnew;
    mnew = fmaxf(mold, pm);
    float aa = exp2f(mold - mnew);
    mrun = mnew;
#pragma unroll
    for (int e = 0; e < 4; ++e) {
      float ae = __shfl(aa, gp * 4 + e);
      ol[e] *= ae;
#pragma unroll
      for (int c = 0; c < 4; ++c) o[c][e] *= ae;
    }
  }
#pragma unroll
  for (int jj = 0; jj < 4; ++jj) {
    bf16x4 pw;
#pragma unroll
    for (int e = 0; e < 4; ++e) pw[e] = (bf16_t)exp2f(s[jj][e] - mnew);
    *(bf16x4*)(Pw + cl * 128 + ((jj * 32 + gp * 8) ^ swz)) = pw;
  }

  asm volatile("" ::: "memory");              // P writes before P reads (same wave)
  bf16x8 pa0 = *(const bf16x8*)(Pw + cl * 128 + ((gp * 16) ^ swz));
  bf16x8 pa1 = *(const bf16x8*)(Pw + cl * 128 + ((64 + gp * 16) ^ swz));

  __builtin_amdgcn_s_setprio(1);
  ol = MFMA16(pa0, ones8, ol);                // lsum on the idle MFMA pipe
  ol = MFMA16(pa1, ones8, ol);
#pragma unroll
  for (int c = 0; c < 4; ++c) {
    const char* base = bV + (c * 16 + cl) * 128;
    bf16x8 v0 = *(const bf16x8*)(base + ((gp * 16) ^ swz));
    bf16x8 v1 = *(const bf16x8*)(base + ((64 + gp * 16) ^ swz));
    o[c] = MFMA16(pa0, v0, o[c]);
    o[c] = MFMA16(pa1, v1, o[c]);
  }
  __builtin_amdgcn_s_setprio(0);
  asm volatile("" ::: "memory");              // pa/v reads done before P rewrite
}

// ---- attention: QBLK=64, paired q-tiles (jL, 31-jL), 4 blocks/CU ----
__global__ __launch_bounds__(256, 4) void k_attn6(const bf16_t* __restrict__ qh,
                                                  const bf16_t* __restrict__ kh,
                                                  const bf16_t* __restrict__ vT,
                                                  bf16_t* __restrict__ out) {
  __shared__ alignas(16) char sK[2][8192];     // [64 kv][128B d], XOR-swizzled
  __shared__ alignas(16) char sV[2][8192];     // [64 d][128B kv], XOR-swizzled
  __shared__ alignas(16) char sP[4][2048];     // per wave: 16q x 128B P buffer

  int n = blockIdx.x;
  int bh = ((n & 7) << 3) | ((n >> 3) & 7);    // same head group -> same XCD
  int pr = n >> 6;                             // 0..15
  int jL = pr, jH = 31 - pr;                   // paired q-tiles: uniform work
  int b = bh >> 4;
  int tid = threadIdx.x, wid = tid >> 6, lane = tid & 63;
  int cl = lane & 15, gp = lane >> 4;

  int qwL = jL * 64 + wid * 16;
  int qwH = jH * 64 + wid * 16;

  // Q fragments (B-operand) from compact qh: col=cl(q), k(d)=gp*8+e
  bf16x8 qL0, qL1, qH0, qH1;
  {
    const bf16_t* p = qh + ((size_t)bh * 2048 + qwL + cl) * 64 + gp * 8;
    qL0 = *(const bf16x8*)p; qL1 = *(const bf16x8*)(p + 32);
    p = qh + ((size_t)bh * 2048 + qwH + cl) * 64 + gp * 8;
    qH0 = *(const bf16x8*)p; qH1 = *(const bf16x8*)(p + 32);
  }
  bf16x8 ones8;
#pragma unroll
  for (int e = 0; e < 8; ++e) ones8[e] = (bf16_t)1.0f;

  int srow = tid >> 3;
  int swzcb = ((tid & 7) * 16) ^ ((srow & 7) << 4);
  const bf16_t* gK = kh + ((size_t)bh * 2048 + srow) * 64 + (swzcb >> 1);
  const bf16_t* gV = vT + ((size_t)(bh * 64) + srow) * 2048 + (swzcb >> 1);

  f32x4 oL[4], oH[4], olL = zero4(), olH = zero4();
#pragma unroll
  for (int c = 0; c < 4; ++c) { oL[c] = zero4(); oH[c] = zero4(); }
  float mrunL = -1e30f, mrunH = -1e30f;

  int swz = (cl & 7) << 4;
  int nt = jH + 1;                             // KV64 tiles (H's causal extent)
  char* Pw = sP[wid];

  {
    char* lK = sK[0] + wid * 1024;
    char* lV = sV[0] + wid * 1024;
    GLOAD_LDS16(gK, lK);
    GLOAD_LDS16(gK + 32 * 64, lK + 4096);
    GLOAD_LDS16(gV, lV);
    GLOAD_LDS16(gV + (size_t)32 * 2048, lV + 4096);
  }
  asm volatile("s_waitcnt vmcnt(0)");
  __syncthreads();

  for (int t = 0; t < nt; ++t) {
    int cur = t & 1;
    int kv0 = t * 64;
    if (t + 1 < nt) {
      int kv1 = kv0 + 64;
      char* lK = sK[cur ^ 1] + wid * 1024;
      char* lV = sV[cur ^ 1] + wid * 1024;
      GLOAD_LDS16(gK + (size_t)kv1 * 64, lK);
      GLOAD_LDS16(gK + (size_t)(kv1 + 32) * 64, lK + 4096);
      GLOAD_LDS16(gV + kv1, lV);
      GLOAD_LDS16(gV + kv1 + (size_t)32 * 2048, lV + 4096);
    }
    const char* bK = sK[cur];
    const char* bV = sV[cur];

    if (t <= jL)
      pass16(bK, bV, Pw, qL0, qL1, ones8, oL, olL, mrunL, kv0, qwL, swz, cl, gp);
    pass16(bK, bV, Pw, qH0, qH1, ones8, oH, olH, mrunH, kv0, qwH, swz, cl, gp);

    asm volatile("s_waitcnt vmcnt(0)");
    __syncthreads();
  }

  // epilogue: lsum already in acc-row domain (ol[e] = row gp*4+e) -> no shuffles
#pragma unroll
  for (int e = 0; e < 4; ++e) {
    float iL = 1.0f / olL[e];
    float iH = 1.0f / olH[e];
    int rL = qwL + gp * 4 + e;
    int rH = qwH + gp * 4 + e;
    int h = bh & 15;
#pragma unroll
    for (int c = 0; c < 4; ++c) {
      int col = h * 64 + c * 16 + cl;
      out[(size_t)(b * 2048 + rL) * 1024 + col] = (bf16_t)(oL[c][e] * iL);
      out[(size_t)(b * 2048 + rH) * 1024 + col] = (bf16_t)(oH[c][e] * iH);
    }
  }
}

// ---------------------------------------------------------------------------
extern "C" void kernel_launch(void* const* d_in, const int* in_sizes, int n_in,
                              void* d_out, int out_size, void* d_ws, size_t ws_size,
                              hipStream_t stream) {
  const float* x      = (const float*)d_in[0];
  const float* w_qkv  = (const float*)d_in[1];
  const float* w_proj = (const float*)d_in[2];
  const float* b_proj = (const float*)d_in[3];
  float* outp = (float*)d_out;

  char* ws = (char*)d_ws;
  bf16_t* xb     = (bf16_t*)(ws);                    // 16 MiB
  bf16_t* wqkvT  = (bf16_t*)(ws + (16u << 20));      // 6 MiB
  bf16_t* wprojT = (bf16_t*)(ws + (22u << 20));      // 2 MiB
  bf16_t* qh     = (bf16_t*)(ws + (24u << 20));      // 16 MiB
  bf16_t* kh     = (bf16_t*)(ws + (40u << 20));      // 16 MiB
  bf16_t* vT     = (bf16_t*)(ws + (56u << 20));      // 16 MiB
  bf16_t* aout   = (bf16_t*)(ws + (72u << 20));      // 16 MiB

  k_cast<<<dim3(8192 * 1024 / (256 * 8)), 256, 0, stream>>>(x, xb);
  k_tcast<<<dim3(3072 / 64, 1024 / 64), 256, 0, stream>>>(w_qkv, wqkvT, 1024, 3072);
  k_tcast<<<dim3(1024 / 64, 1024 / 64), 256, 0, stream>>>(w_proj, wprojT, 1024, 1024);
  k_gemm_qkv<<<dim3(3072 / 128, 8192 / 128), 256, 0, stream>>>(xb, wqkvT, qh, kh, vT);
  k_attn6<<<dim3(1024), 256, 0, stream>>>(qh, kh, vT, aout);
  k_gemm_proj<<<dim3(1024 / 128, 8192 / 128), 256, 0, stream>>>(
      aout, wprojT, outp, b_proj, 8192, 1024, 1024);
}